// Round 3
// baseline (603.977 us; speedup 1.0000x reference)
//
#include <hip/hip_runtime.h>

typedef unsigned short u16;
typedef unsigned int u32;
typedef __bf16 bf16x8 __attribute__((ext_vector_type(8)));
typedef float f32x4 __attribute__((ext_vector_type(4)));
typedef float f32x16 __attribute__((ext_vector_type(16)));
typedef unsigned short u16x4 __attribute__((ext_vector_type(4)));

#define AS1(p) ((const __attribute__((address_space(1))) void*)(p))
#define AS3(p) ((__attribute__((address_space(3))) void*)(p))

__device__ __forceinline__ u16 f2bf(float x) {
  u32 u = __float_as_uint(x);
  u32 r = u + 0x7fffu + ((u >> 16) & 1u);
  return (u16)(r >> 16);
}
__device__ __forceinline__ float bf2f(u16 h) {
  return __uint_as_float(((u32)h) << 16);
}

// ---------------------------------------------------------------------------
// split fp32 -> (bf16 hi, bf16 lo) for q and k.
// ---------------------------------------------------------------------------
__device__ __forceinline__ void split4(float4 x, u16x4& h, u16x4& l) {
  float xs[4] = {x.x, x.y, x.z, x.w};
#pragma unroll
  for (int e = 0; e < 4; ++e) {
    u16 hh = f2bf(xs[e]);
    h[e] = hh;
    l[e] = f2bf(xs[e] - bf2f(hh));
  }
}

__global__ __launch_bounds__(256) void split_qk(
    const float* __restrict__ q, const float* __restrict__ k,
    u16* __restrict__ qh, u16* __restrict__ ql, u16* __restrict__ kh,
    u16* __restrict__ kl, int n4) {
  int stride = gridDim.x * blockDim.x;
  for (int i = blockIdx.x * blockDim.x + threadIdx.x; i < n4; i += stride) {
    u16x4 h, l;
    float4 x = ((const float4*)q)[i];
    split4(x, h, l);
    ((u16x4*)qh)[i] = h;
    ((u16x4*)ql)[i] = l;
    x = ((const float4*)k)[i];
    split4(x, h, l);
    ((u16x4*)kh)[i] = h;
    ((u16x4*)kl)[i] = l;
  }
}

// Weight prep: wqt = split(Wq^T); wot = bf16(Wo^T); wq_b = bf16(Wq) row-major.
__global__ void prep_w_t(const float* __restrict__ Wq,
                         const float* __restrict__ Wo, u16* __restrict__ wqt_h,
                         u16* __restrict__ wqt_l, u16* __restrict__ wot,
                         u16* __restrict__ wq_b, int D) {
  __shared__ float tq[32][33];
  __shared__ float to[32][33];
  int c0 = blockIdx.x * 32, r0 = blockIdx.y * 32;
  int tx = threadIdx.x, ty = threadIdx.y;
#pragma unroll
  for (int i = ty; i < 32; i += 8) {
    float xq = Wq[(size_t)(r0 + i) * D + c0 + tx];
    tq[i][tx] = xq;
    wq_b[(size_t)(r0 + i) * D + c0 + tx] = f2bf(xq);
    to[i][tx] = Wo[(size_t)(r0 + i) * D + c0 + tx];
  }
  __syncthreads();
#pragma unroll
  for (int i = ty; i < 32; i += 8) {
    float x = tq[tx][i];  // = Wq[(r0+tx)][c0+i]
    u16 h = f2bf(x);
    size_t o = (size_t)(c0 + i) * D + r0 + tx;
    wqt_h[o] = h;
    wqt_l[o] = f2bf(x - bf2f(h));
    wot[o] = f2bf(to[tx][i]);
  }
}

// Batched transpose f32 -> bf16: out[z][c][r] = bf16(in[z][r][c])
__global__ void transpose_f32_bf16(const float* __restrict__ in,
                                   u16* __restrict__ out, int R, int C) {
  __shared__ float tile[32][33];
  size_t zi = (size_t)blockIdx.z * R * C;
  int c0 = blockIdx.x * 32, r0 = blockIdx.y * 32;
  int tx = threadIdx.x, ty = threadIdx.y;
#pragma unroll
  for (int i = ty; i < 32; i += 8)
    tile[i][tx] = in[zi + (size_t)(r0 + i) * C + (c0 + tx)];
  __syncthreads();
#pragma unroll
  for (int i = ty; i < 32; i += 8)
    out[zi + (size_t)(c0 + i) * R + (r0 + tx)] = f2bf(tile[tx][i]);
}

// bqo[f] = sum_e bq[e]*Wo[e][f] + bo[f]
__global__ __launch_bounds__(256) void bqo_kernel(const float* __restrict__ bq,
                                                  const float* __restrict__ Wo,
                                                  const float* __restrict__ bo,
                                                  float* __restrict__ bqo,
                                                  int D) {
  int f = blockIdx.x * 256 + threadIdx.x;
  float s = bo[f];
  for (int e = 0; e < D; ++e) s += bq[e] * Wo[(size_t)e * D + f];
  bqo[f] = s;
}

// ---------------------------------------------------------------------------
// 128x128 2-barrier GEMM for the small plain GEMMs (Wqo / ctx / outproj).
// C[m][n] = sum_k A[m][k]*Bt[n][k] (+bias); EPI: 0=f32, 1=bf16.
// ---------------------------------------------------------------------------
template <int EPI>
__global__ __launch_bounds__(256, 2) void gemm_bt(
    const u16* __restrict__ Ah, const u16* __restrict__ Bh,
    const float* __restrict__ bias, float* __restrict__ Cf,
    u16* __restrict__ Ch, int M, int N, int K,
    long long sA, long long sB, long long sC) {
  __shared__ alignas(16) u16 As[128 * 32];
  __shared__ alignas(16) u16 Bs[128 * 32];

  const int t = threadIdx.x;
  const int lane = t & 63;
  const int w = t >> 6;
  const int wr = w >> 1, wc = w & 1;

  const long long zb = blockIdx.z;
  const u16* pA = Ah + zb * sA;
  const u16* pB = Bh + zb * sB;

  const int m0 = blockIdx.x * 128;
  const int n0 = blockIdx.y * 128;

  f32x4 acc[4][4] = {};

  const int row0 = t >> 2;
  const int colS = (t & 3) * 8;
  const int lds0 = (t & ~63) * 8;
  const int lds1 = (256 + (t & ~63)) * 8;

  const size_t aoff0 = (size_t)(m0 + row0) * K + colS;
  const size_t aoff1 = (size_t)(m0 + row0 + 64) * K + colS;
  const size_t boff0 = (size_t)(n0 + row0) * K + colS;
  const size_t boff1 = (size_t)(n0 + row0 + 64) * K + colS;

  for (int k0 = 0; k0 < K; k0 += 32) {
    __syncthreads();
    __builtin_amdgcn_global_load_lds(AS1(pA + aoff0 + k0), AS3(&As[lds0]), 16, 0, 0);
    __builtin_amdgcn_global_load_lds(AS1(pA + aoff1 + k0), AS3(&As[lds1]), 16, 0, 0);
    __builtin_amdgcn_global_load_lds(AS1(pB + boff0 + k0), AS3(&Bs[lds0]), 16, 0, 0);
    __builtin_amdgcn_global_load_lds(AS1(pB + boff1 + k0), AS3(&Bs[lds1]), 16, 0, 0);
    __syncthreads();

    const int fr = lane & 15;
    const int kc = (lane >> 4) * 8;
    bf16x8 a[4], b[4];
#pragma unroll
    for (int i = 0; i < 4; ++i)
      a[i] = *(const bf16x8*)&As[(wr * 64 + i * 16 + fr) * 32 + kc];
#pragma unroll
    for (int j = 0; j < 4; ++j)
      b[j] = *(const bf16x8*)&Bs[(wc * 64 + j * 16 + fr) * 32 + kc];
#pragma unroll
    for (int i = 0; i < 4; ++i)
#pragma unroll
      for (int j = 0; j < 4; ++j)
        acc[i][j] = __builtin_amdgcn_mfma_f32_16x16x32_bf16(a[i], b[j], acc[i][j], 0, 0, 0);
  }

  const int er = (lane >> 4) * 4;
  const int ec = lane & 15;
#pragma unroll
  for (int j = 0; j < 4; ++j) {
    const int gcol = n0 + wc * 64 + j * 16 + ec;
    const float bv = bias ? bias[gcol] : 0.0f;
#pragma unroll
    for (int i = 0; i < 4; ++i) {
      const int grow0 = m0 + wr * 64 + i * 16 + er;
#pragma unroll
      for (int r = 0; r < 4; ++r) {
        const float x = acc[i][j][r] + bv;
        const size_t off = (size_t)zb * sC + (size_t)(grow0 + r) * N + gcol;
        if constexpr (EPI == 0) Cf[off] = x;
        else Ch[off] = f2bf(x);
      }
    }
  }
}

// ---------------------------------------------------------------------------
// 256x256 8-phase split GEMM, 32x32x16 MFMA, Markidis 3-term.
// K-tile = 32 real K packed as 64 virtual-K (hi chunks 0-3, lo 4-7).
// Phases per K-tile: (qm,s) in {(0,0),(1,0),(0,1),(1,1)} -> balanced 8/8/4/4
// ds_reads; term-major MFMA (12 x 32x32x16, dep distance 4). 512 threads,
// 128 KiB dyn LDS, XOR-swizzle, counted vmcnt(4) at P4/P8, setprio.
// EPI: 0 = f32 out (+bias), 2 = bf16 hi/lo split out (+bias).
// ---------------------------------------------------------------------------
#define A_LDS(BUF, H) ((BUF) * 32768 + (H) * 8192)
#define B_LDS(BUF, H) ((BUF) * 32768 + 16384 + (H) * 8192)

#define STAGE(DSTBASE, SH, SL, ROWBASE, KREAL)                                 \
  do {                                                                         \
    const u16* s0_ = (sc < 4 ? (SH) : (SL)) +                                  \
                     (size_t)((ROWBASE) + sr) * K + (KREAL) + ((sc & 3) << 3); \
    const u16* s1_ = s0_ + (size_t)64 * K;                                     \
    __builtin_amdgcn_global_load_lds(AS1(s0_), AS3(&lds[(DSTBASE) + ldsW]), 16, 0, 0); \
    __builtin_amdgcn_global_load_lds(AS1(s1_), AS3(&lds[(DSTBASE) + 4096 + ldsW]), 16, 0, 0); \
  } while (0)

// A frags for half-tile QM, kstep S: af[fi][plane]
#define LOADA32(BUF, QM, S)                                                    \
  do {                                                                         \
    const int base_ = A_LDS(BUF, QM);                                          \
    _Pragma("unroll") for (int fi_ = 0; fi_ < 2; ++fi_) {                      \
      const int r_ = wr * 64 + fi_ * 32 + ln31;                                \
      _Pragma("unroll") for (int p_ = 0; p_ < 2; ++p_) {                       \
        const int ch_ = p_ * 4 + (S) * 2 + khalf;                              \
        af[fi_][p_] = *(const bf16x8*)&lds[base_ + r_ * 64 + ((ch_ ^ (r_ & 7)) << 3)]; \
      }                                                                        \
    }                                                                          \
  } while (0)

// B frags for kstep S (both col-halves): bf[qn][plane][S]
#define LOADB32(BUF, S)                                                        \
  do {                                                                         \
    _Pragma("unroll") for (int qn_ = 0; qn_ < 2; ++qn_) {                      \
      const int base_ = B_LDS(BUF, qn_);                                       \
      const int r_ = wc * 32 + ln31;                                           \
      _Pragma("unroll") for (int p_ = 0; p_ < 2; ++p_) {                       \
        const int ch_ = p_ * 4 + (S) * 2 + khalf;                              \
        bfr[qn_][p_][S] = *(const bf16x8*)&lds[base_ + r_ * 64 + ((ch_ ^ (r_ & 7)) << 3)]; \
      }                                                                        \
    }                                                                          \
  } while (0)

// 12 MFMA, term-major: (pa,pb) = (0,0),(0,1),(1,0)
#define MMAQ32(QM, S)                                                          \
  do {                                                                         \
    _Pragma("unroll") for (int t_ = 0; t_ < 3; ++t_) {                         \
      const int pa_ = (t_ == 2) ? 1 : 0;                                       \
      const int pb_ = (t_ == 1) ? 1 : 0;                                       \
      _Pragma("unroll") for (int fi_ = 0; fi_ < 2; ++fi_) {                    \
        _Pragma("unroll") for (int qn_ = 0; qn_ < 2; ++qn_) {                  \
          acc[(QM) * 2 + fi_][qn_] = __builtin_amdgcn_mfma_f32_32x32x16_bf16(  \
              af[fi_][pa_], bfr[qn_][pb_][S], acc[(QM) * 2 + fi_][qn_], 0, 0, 0); \
        }                                                                      \
      }                                                                        \
    }                                                                          \
  } while (0)

#define PH_PRE()                                                               \
  __builtin_amdgcn_s_barrier();                                                \
  asm volatile("s_waitcnt lgkmcnt(0)" ::: "memory");                           \
  __builtin_amdgcn_s_setprio(1)

#define PH_POST()                                                              \
  __builtin_amdgcn_s_setprio(0);                                               \
  __builtin_amdgcn_s_barrier()

template <int EPI>
__global__ __launch_bounds__(512, 2) void gemm8s(
    const u16* __restrict__ Ah, const u16* __restrict__ Al,
    const u16* __restrict__ Bh, const u16* __restrict__ Bl,
    const float* __restrict__ bias, float* __restrict__ Cf,
    u16* __restrict__ Ch, u16* __restrict__ Cl, int M, int N, int K,
    long long sA, long long sB, long long sC) {
  extern __shared__ u16 lds[];

  const int tt = threadIdx.x;
  const int lane = tt & 63;
  const int wv = tt >> 6;
  const int wr = wv >> 2;    // 0..1
  const int wc = wv & 3;     // 0..3
  const int ln31 = lane & 31;
  const int khalf = lane >> 5;

  const long long zb = blockIdx.z;
  const u16* pAh = Ah + zb * sA;
  const u16* pAl = Al + zb * sA;
  const u16* pBh = Bh + zb * sB;
  const u16* pBl = Bl + zb * sB;
  const int m0 = blockIdx.x * 256;
  const int n0 = blockIdx.y * 256;

  const int sr = tt >> 3;
  const int ss = tt & 7;
  const int sc = ss ^ (sr & 7);
  const int ldsW = (tt & ~63) * 8;

  f32x16 acc[4][2] = {};
  bf16x8 af[2][2], bfr[2][2][2];

  const int NT = K / 32;
  const int NITER = NT / 2;

  // prologue: tile0 full + tile1 B-halves
  STAGE(A_LDS(0, 0), pAh, pAl, m0, 0);
  STAGE(A_LDS(0, 1), pAh, pAl, m0 + 128, 0);
  STAGE(B_LDS(0, 0), pBh, pBl, n0, 0);
  STAGE(B_LDS(0, 1), pBh, pBl, n0 + 128, 0);
  STAGE(B_LDS(1, 0), pBh, pBl, n0, 32);
  STAGE(B_LDS(1, 1), pBh, pBl, n0 + 32 * 0 + 128, 32);
  asm volatile("s_waitcnt vmcnt(4)" ::: "memory");
  __builtin_amdgcn_s_barrier();
  __builtin_amdgcn_sched_barrier(0);

  for (int it = 0; it < NITER; ++it) {
    const int t0 = 2 * it;
    const int k1 = (t0 + 1) * 32;
    const int k2 = (t0 + 2 < NT ? t0 + 2 : NT - 1) * 32;
    const int k3 = (t0 + 3 < NT ? t0 + 3 : NT - 1) * 32;

    // P1: (qm0,s0) buf0 | stage A(1,h0) <- t1
    LOADA32(0, 0, 0);
    LOADB32(0, 0);
    STAGE(A_LDS(1, 0), pAh, pAl, m0, k1);
    PH_PRE();
    MMAQ32(0, 0);
    PH_POST();

    // P2: (qm1,s0) buf0 | preload B s1 | stage A(1,h1) <- t1
    LOADA32(0, 1, 0);
    LOADB32(0, 1);
    STAGE(A_LDS(1, 1), pAh, pAl, m0 + 128, k1);
    PH_PRE();
    MMAQ32(1, 0);
    PH_POST();

    // P3: (qm0,s1) buf0 | stage B(0,h0) <- t2
    LOADA32(0, 0, 1);
    STAGE(B_LDS(0, 0), pBh, pBl, n0, k2);
    PH_PRE();
    MMAQ32(0, 1);
    PH_POST();

    // P4: (qm1,s1) buf0 | stage B(0,h1) <- t2 | vmcnt(4)
    LOADA32(0, 1, 1);
    STAGE(B_LDS(0, 1), pBh, pBl, n0 + 128, k2);
    __builtin_amdgcn_s_barrier();
    asm volatile("s_waitcnt lgkmcnt(0)" ::: "memory");
    __builtin_amdgcn_s_setprio(1);
    MMAQ32(1, 1);
    __builtin_amdgcn_s_setprio(0);
    asm volatile("s_waitcnt vmcnt(4)" ::: "memory");
    __builtin_amdgcn_s_barrier();
    __builtin_amdgcn_sched_barrier(0);

    // P5: (qm0,s0) buf1 | stage A(0,h0) <- t2
    LOADA32(1, 0, 0);
    LOADB32(1, 0);
    STAGE(A_LDS(0, 0), pAh, pAl, m0, k2);
    PH_PRE();
    MMAQ32(0, 0);
    PH_POST();

    // P6: (qm1,s0) buf1 | preload B s1 | stage A(0,h1) <- t2
    LOADA32(1, 1, 0);
    LOADB32(1, 1);
    STAGE(A_LDS(0, 1), pAh, pAl, m0 + 128, k2);
    PH_PRE();
    MMAQ32(1, 0);
    PH_POST();

    // P7: (qm0,s1) buf1 | stage B(1,h0) <- t3
    LOADA32(1, 0, 1);
    STAGE(B_LDS(1, 0), pBh, pBl, n0, k3);
    PH_PRE();
    MMAQ32(0, 1);
    PH_POST();

    // P8: (qm1,s1) buf1 | stage B(1,h1) <- t3 | vmcnt(4)
    LOADA32(1, 1, 1);
    STAGE(B_LDS(1, 1), pBh, pBl, n0 + 128, k3);
    __builtin_amdgcn_s_barrier();
    asm volatile("s_waitcnt lgkmcnt(0)" ::: "memory");
    __builtin_amdgcn_s_setprio(1);
    MMAQ32(1, 1);
    __builtin_amdgcn_s_setprio(0);
    asm volatile("s_waitcnt vmcnt(4)" ::: "memory");
    __builtin_amdgcn_s_barrier();
    __builtin_amdgcn_sched_barrier(0);
  }

  // epilogue: 32x32 C/D map: col = lane&31, row = (reg&3)+8*(reg>>2)+4*(lane>>5)
#pragma unroll
  for (int fg = 0; fg < 4; ++fg) {
    const int qm = fg >> 1, fi = fg & 1;
    const int rbase = m0 + qm * 128 + wr * 64 + fi * 32 + 4 * khalf;
#pragma unroll
    for (int qn = 0; qn < 2; ++qn) {
      const int gcol = n0 + qn * 128 + wc * 32 + ln31;
      const float bv = bias ? bias[gcol] : 0.0f;
#pragma unroll
      for (int r = 0; r < 16; ++r) {
        const int grow = rbase + (r & 3) + 8 * (r >> 2);
        const float x = acc[fg][qn][r] + bv;
        const size_t off = (size_t)zb * sC + (size_t)grow * N + gcol;
        if constexpr (EPI == 0) {
          Cf[off] = x;
        } else {
          const u16 h = f2bf(x);
          Ch[off] = h;
          Cl[off] = f2bf(x - bf2f(h));
        }
      }
    }
  }
}

// ---------------------------------------------------------------------------
// Row softmax: in-place fp32 (weights output) + bf16 copy (P for PV GEMM).
// ---------------------------------------------------------------------------
__global__ __launch_bounds__(256) void softmax_rows(float* __restrict__ S,
                                                    u16* __restrict__ P) {
  const int T = 2048;
  const size_t row = blockIdx.x;
  float* sr = S + row * T;
  u16* pr = P + row * T;
  const int t = threadIdx.x;
  const int w = t >> 6, lane = t & 63;
  __shared__ float red[8];

  float v[8];
  float mx = -1e30f;
#pragma unroll
  for (int i = 0; i < 8; ++i) {
    v[i] = sr[t + 256 * i];
    mx = fmaxf(mx, v[i]);
  }
#pragma unroll
  for (int off = 32; off; off >>= 1) mx = fmaxf(mx, __shfl_xor(mx, off));
  if (lane == 0) red[w] = mx;
  __syncthreads();
  mx = fmaxf(fmaxf(red[0], red[1]), fmaxf(red[2], red[3]));

  float s = 0.f;
#pragma unroll
  for (int i = 0; i < 8; ++i) {
    v[i] = __expf(v[i] - mx);
    s += v[i];
  }
#pragma unroll
  for (int off = 32; off; off >>= 1) s += __shfl_xor(s, off);
  if (lane == 0) red[4 + w] = s;
  __syncthreads();
  s = (red[4] + red[5]) + (red[6] + red[7]);
  const float inv = 1.0f / s;
#pragma unroll
  for (int i = 0; i < 8; ++i) {
    const float wv = v[i] * inv;
    sr[t + 256 * i] = wv;
    pr[t + 256 * i] = f2bf(wv);
  }
}

// ---------------------------------------------------------------------------
extern "C" void kernel_launch(void* const* d_in, const int* in_sizes, int n_in,
                              void* d_out, int out_size, void* d_ws,
                              size_t ws_size, hipStream_t stream) {
  (void)in_sizes; (void)n_in; (void)out_size; (void)ws_size;
  const float* query = (const float*)d_in[0];
  const float* key   = (const float*)d_in[1];
  const float* value = (const float*)d_in[2];
  const float* Wq    = (const float*)d_in[3];
  const float* bq    = (const float*)d_in[4];
  const float* Wo    = (const float*)d_in[5];
  const float* bo    = (const float*)d_in[6];

  const int S = 2048, D = 1024;
  const size_t n = (size_t)4 * S * D;  // 8,388,608

  float* out = (float*)d_out;          // (B,S,D) f32, 32MB
  float* wts = out + n;                // (B,S,T) f32, 64MB

  char* ws = (char*)d_ws;
  u16* wqt_h = (u16*)(ws);                   // 2MB  Wq^T hi
  u16* wqt_l = (u16*)(ws + (2ull << 20));    // 2MB  Wq^T lo
  u16* wot   = (u16*)(ws + (4ull << 20));    // 2MB  Wo^T bf16
  u16* wq_b  = (u16*)(ws + (6ull << 20));    // 2MB  Wq bf16 row-major
  u16* wqoT  = (u16*)(ws + (8ull << 20));    // 2MB  (Wq@Wo)^T bf16
  float* bqo = (float*)(ws + (10ull << 20)); // 4KB
  u16* QKh   = (u16*)(ws + (12ull << 20));   // 32MB: Q rows then K rows
  u16* QKl   = (u16*)(ws + (44ull << 20));   // 32MB  (total ws: 76MB)
  u16* P   = QKh;  // 32MB (QKh dead after score GEMM)
  u16* tmp = QKl;  // 16MB (QKl dead after score GEMM); tmp = P@value^T

  // scratch in d_out: wts region holds input splits until score GEMM writes;
  // out region holds value^T until the final GEMM writes.
  u16* qkin_h = (u16*)wts;  // [q(8192 rows); k(8192 rows)]
  u16* qkin_l = qkin_h + 2 * n;
  u16* valT = (u16*)out;    // (B, D, T) bf16, 16MB

  hipFuncSetAttribute((const void*)&gemm8s<2>,
                      hipFuncAttributeMaxDynamicSharedMemorySize, 131072);
  hipFuncSetAttribute((const void*)&gemm8s<0>,
                      hipFuncAttributeMaxDynamicSharedMemorySize, 131072);

  // 1. split q,k inputs (stacked)
  split_qk<<<2048, 256, 0, stream>>>(query, key, qkin_h, qkin_l, qkin_h + n,
                                     qkin_l + n, (int)(n / 4));
  // 2. weight prep
  prep_w_t<<<dim3(D / 32, D / 32), dim3(32, 8), 0, stream>>>(
      Wq, Wo, wqt_h, wqt_l, wot, wq_b, D);
  // 3. value^T (f32 -> bf16), per batch
  transpose_f32_bf16<<<dim3(D / 32, S / 32, 4), dim3(32, 8), 0, stream>>>(
      value, valT, S, D);
  // 4. WqoT[f][e] = sum_d Wo^T[f][d] * Wq[e][d]   (= (Wq@Wo)^T)
  gemm_bt<1><<<dim3(8, 8, 1), 256, 0, stream>>>(
      wot, wq_b, nullptr, nullptr, wqoT, 1024, 1024, 1024, 0, 0, 0);
  // 5. bqo = bq@Wo + bo
  bqo_kernel<<<4, 256, 0, stream>>>(bq, Wo, bo, bqo, D);
  // 6. [Q;K] = [q;k] @ Wq + bq  (split in, split out) — 8-phase 256^2
  gemm8s<2><<<dim3(64, 4, 1), 512, 131072, stream>>>(
      qkin_h, qkin_l, wqt_h, wqt_l, bq, nullptr, QKh, QKl, 16384, 1024, 1024,
      0, 0, 0);
  // 7. score = Q @ K^T (split, fp32 out into weights region) — 8-phase 256^2
  gemm8s<0><<<dim3(8, 8, 4), 512, 131072, stream>>>(
      QKh, QKl, QKh + n, QKl + n, nullptr, wts, nullptr, nullptr, 2048, 2048,
      1024, (long long)S * D, (long long)S * D, (long long)S * S);
  // 8. softmax rows (in-place) + bf16 P
  softmax_rows<<<8192, 256, 0, stream>>>(wts, P);
  // 9. tmp = P @ value^T   (Bt = valT, K-major)
  gemm_bt<1><<<dim3(16, 8, 4), 256, 0, stream>>>(
      P, valT, nullptr, nullptr, tmp, 2048, 1024, 2048, (long long)S * S,
      (long long)D * S, (long long)S * D);
  // 10. out = tmp @ Wqo + bqo   (Bt = WqoT)
  gemm_bt<0><<<dim3(64, 8, 1), 256, 0, stream>>>(
      tmp, wqoT, bqo, out, nullptr, 8192, 1024, 1024, 0, 0, 0);
}

// Round 4
// 370.571 us; speedup vs baseline: 1.6299x; 1.6299x over previous
//
#include <hip/hip_runtime.h>

typedef unsigned short u16;
typedef unsigned int u32;
typedef __bf16 bf16x8 __attribute__((ext_vector_type(8)));
typedef float f32x4 __attribute__((ext_vector_type(4)));
typedef float f32x16 __attribute__((ext_vector_type(16)));
typedef unsigned short u16x4 __attribute__((ext_vector_type(4)));

#define AS1(p) ((const __attribute__((address_space(1))) void*)(p))
#define AS3(p) ((__attribute__((address_space(3))) void*)(p))

__device__ __forceinline__ u16 f2bf(float x) {
  u32 u = __float_as_uint(x);
  u32 r = u + 0x7fffu + ((u >> 16) & 1u);
  return (u16)(r >> 16);
}
__device__ __forceinline__ float bf2f(u16 h) {
  return __uint_as_float(((u32)h) << 16);
}

// ---------------------------------------------------------------------------
// split fp32 -> (bf16 hi, bf16 lo) for q and k.
// ---------------------------------------------------------------------------
__device__ __forceinline__ void split4(float4 x, u16x4& h, u16x4& l) {
  float xs[4] = {x.x, x.y, x.z, x.w};
#pragma unroll
  for (int e = 0; e < 4; ++e) {
    u16 hh = f2bf(xs[e]);
    h[e] = hh;
    l[e] = f2bf(xs[e] - bf2f(hh));
  }
}

__global__ __launch_bounds__(256) void split_qk(
    const float* __restrict__ q, const float* __restrict__ k,
    u16* __restrict__ qh, u16* __restrict__ ql, u16* __restrict__ kh,
    u16* __restrict__ kl, int n4) {
  int stride = gridDim.x * blockDim.x;
  for (int i = blockIdx.x * blockDim.x + threadIdx.x; i < n4; i += stride) {
    u16x4 h, l;
    float4 x = ((const float4*)q)[i];
    split4(x, h, l);
    ((u16x4*)qh)[i] = h;
    ((u16x4*)ql)[i] = l;
    x = ((const float4*)k)[i];
    split4(x, h, l);
    ((u16x4*)kh)[i] = h;
    ((u16x4*)kl)[i] = l;
  }
}

// Weight prep: wqt = split(Wq^T); wot = bf16(Wo^T); wq_b = bf16(Wq) row-major.
__global__ void prep_w_t(const float* __restrict__ Wq,
                         const float* __restrict__ Wo, u16* __restrict__ wqt_h,
                         u16* __restrict__ wqt_l, u16* __restrict__ wot,
                         u16* __restrict__ wq_b, int D) {
  __shared__ float tq[32][33];
  __shared__ float to[32][33];
  int c0 = blockIdx.x * 32, r0 = blockIdx.y * 32;
  int tx = threadIdx.x, ty = threadIdx.y;
#pragma unroll
  for (int i = ty; i < 32; i += 8) {
    float xq = Wq[(size_t)(r0 + i) * D + c0 + tx];
    tq[i][tx] = xq;
    wq_b[(size_t)(r0 + i) * D + c0 + tx] = f2bf(xq);
    to[i][tx] = Wo[(size_t)(r0 + i) * D + c0 + tx];
  }
  __syncthreads();
#pragma unroll
  for (int i = ty; i < 32; i += 8) {
    float x = tq[tx][i];  // = Wq[(r0+tx)][c0+i]
    u16 h = f2bf(x);
    size_t o = (size_t)(c0 + i) * D + r0 + tx;
    wqt_h[o] = h;
    wqt_l[o] = f2bf(x - bf2f(h));
    wot[o] = f2bf(to[tx][i]);
  }
}

// Batched transpose f32 -> bf16: out[z][c][r] = bf16(in[z][r][c])
__global__ void transpose_f32_bf16(const float* __restrict__ in,
                                   u16* __restrict__ out, int R, int C) {
  __shared__ float tile[32][33];
  size_t zi = (size_t)blockIdx.z * R * C;
  int c0 = blockIdx.x * 32, r0 = blockIdx.y * 32;
  int tx = threadIdx.x, ty = threadIdx.y;
#pragma unroll
  for (int i = ty; i < 32; i += 8)
    tile[i][tx] = in[zi + (size_t)(r0 + i) * C + (c0 + tx)];
  __syncthreads();
#pragma unroll
  for (int i = ty; i < 32; i += 8)
    out[zi + (size_t)(c0 + i) * R + (r0 + tx)] = f2bf(tile[tx][i]);
}

// bqo[f] = sum_e bq[e]*Wo[e][f] + bo[f]   via wot (Wo^T bf16, row-contiguous).
// One wave per f: lanes stride e (coalesced), shuffle-reduce. 256 blocks.
__global__ __launch_bounds__(256) void bqo_kernel(const float* __restrict__ bq,
                                                  const u16* __restrict__ wot,
                                                  const float* __restrict__ bo,
                                                  float* __restrict__ bqo,
                                                  int D) {
  const int f = blockIdx.x * 4 + (threadIdx.x >> 6);
  const int lane = threadIdx.x & 63;
  const u16* wr_ = wot + (size_t)f * D;
  float s = 0.f;
  for (int e = lane; e < D; e += 64) s += bq[e] * bf2f(wr_[e]);
#pragma unroll
  for (int off = 32; off; off >>= 1) s += __shfl_xor(s, off);
  if (lane == 0) bqo[f] = s + bo[f];
}

// ---------------------------------------------------------------------------
// 128x128 2-barrier GEMM for the small plain GEMMs (Wqo / ctx / outproj).
// C[m][n] = sum_k A[m][k]*Bt[n][k] (+bias); EPI: 0=f32, 1=bf16.
// ---------------------------------------------------------------------------
template <int EPI>
__global__ __launch_bounds__(256, 2) void gemm_bt(
    const u16* __restrict__ Ah, const u16* __restrict__ Bh,
    const float* __restrict__ bias, float* __restrict__ Cf,
    u16* __restrict__ Ch, int M, int N, int K,
    long long sA, long long sB, long long sC) {
  __shared__ alignas(16) u16 As[128 * 32];
  __shared__ alignas(16) u16 Bs[128 * 32];

  const int t = threadIdx.x;
  const int lane = t & 63;
  const int w = t >> 6;
  const int wr = w >> 1, wc = w & 1;

  const long long zb = blockIdx.z;
  const u16* pA = Ah + zb * sA;
  const u16* pB = Bh + zb * sB;

  const int m0 = blockIdx.x * 128;
  const int n0 = blockIdx.y * 128;

  f32x4 acc[4][4] = {};

  const int row0 = t >> 2;
  const int colS = (t & 3) * 8;
  const int lds0 = (t & ~63) * 8;
  const int lds1 = (256 + (t & ~63)) * 8;

  const size_t aoff0 = (size_t)(m0 + row0) * K + colS;
  const size_t aoff1 = (size_t)(m0 + row0 + 64) * K + colS;
  const size_t boff0 = (size_t)(n0 + row0) * K + colS;
  const size_t boff1 = (size_t)(n0 + row0 + 64) * K + colS;

  for (int k0 = 0; k0 < K; k0 += 32) {
    __syncthreads();
    __builtin_amdgcn_global_load_lds(AS1(pA + aoff0 + k0), AS3(&As[lds0]), 16, 0, 0);
    __builtin_amdgcn_global_load_lds(AS1(pA + aoff1 + k0), AS3(&As[lds1]), 16, 0, 0);
    __builtin_amdgcn_global_load_lds(AS1(pB + boff0 + k0), AS3(&Bs[lds0]), 16, 0, 0);
    __builtin_amdgcn_global_load_lds(AS1(pB + boff1 + k0), AS3(&Bs[lds1]), 16, 0, 0);
    __syncthreads();

    const int fr = lane & 15;
    const int kc = (lane >> 4) * 8;
    bf16x8 a[4], b[4];
#pragma unroll
    for (int i = 0; i < 4; ++i)
      a[i] = *(const bf16x8*)&As[(wr * 64 + i * 16 + fr) * 32 + kc];
#pragma unroll
    for (int j = 0; j < 4; ++j)
      b[j] = *(const bf16x8*)&Bs[(wc * 64 + j * 16 + fr) * 32 + kc];
#pragma unroll
    for (int i = 0; i < 4; ++i)
#pragma unroll
      for (int j = 0; j < 4; ++j)
        acc[i][j] = __builtin_amdgcn_mfma_f32_16x16x32_bf16(a[i], b[j], acc[i][j], 0, 0, 0);
  }

  const int er = (lane >> 4) * 4;
  const int ec = lane & 15;
#pragma unroll
  for (int j = 0; j < 4; ++j) {
    const int gcol = n0 + wc * 64 + j * 16 + ec;
    const float bv = bias ? bias[gcol] : 0.0f;
#pragma unroll
    for (int i = 0; i < 4; ++i) {
      const int grow0 = m0 + wr * 64 + i * 16 + er;
#pragma unroll
      for (int r = 0; r < 4; ++r) {
        const float x = acc[i][j][r] + bv;
        const size_t off = (size_t)zb * sC + (size_t)(grow0 + r) * N + gcol;
        if constexpr (EPI == 0) Cf[off] = x;
        else Ch[off] = f2bf(x);
      }
    }
  }
}

// ---------------------------------------------------------------------------
// 256x256 8-phase split GEMM, 32x32x16 MFMA, Markidis 3-term.
// K-tile = 32 real K packed as 64 virtual-K (hi chunks 0-3, lo 4-7).
// Phases per K-tile: (qm,s) in {(0,0),(1,0),(0,1),(1,1)} -> balanced 8/8/4/4
// ds_reads; term-major MFMA (12 x 32x32x16, dep distance 4). 512 threads,
// 128 KiB dyn LDS, XOR-swizzle, counted vmcnt(4) at P4/P8, setprio.
// EPI: 0 = f32 out (+bias), 2 = bf16 hi/lo split out (+bias).
// ---------------------------------------------------------------------------
#define A_LDS(BUF, H) ((BUF) * 32768 + (H) * 8192)
#define B_LDS(BUF, H) ((BUF) * 32768 + 16384 + (H) * 8192)

#define STAGE(DSTBASE, SH, SL, ROWBASE, KREAL)                                 \
  do {                                                                         \
    const u16* s0_ = (sc < 4 ? (SH) : (SL)) +                                  \
                     (size_t)((ROWBASE) + sr) * K + (KREAL) + ((sc & 3) << 3); \
    const u16* s1_ = s0_ + (size_t)64 * K;                                     \
    __builtin_amdgcn_global_load_lds(AS1(s0_), AS3(&lds[(DSTBASE) + ldsW]), 16, 0, 0); \
    __builtin_amdgcn_global_load_lds(AS1(s1_), AS3(&lds[(DSTBASE) + 4096 + ldsW]), 16, 0, 0); \
  } while (0)

// A frags for half-tile QM, kstep S: af[fi][plane]
#define LOADA32(BUF, QM, S)                                                    \
  do {                                                                         \
    const int base_ = A_LDS(BUF, QM);                                          \
    _Pragma("unroll") for (int fi_ = 0; fi_ < 2; ++fi_) {                      \
      const int r_ = wr * 64 + fi_ * 32 + ln31;                                \
      _Pragma("unroll") for (int p_ = 0; p_ < 2; ++p_) {                       \
        const int ch_ = p_ * 4 + (S) * 2 + khalf;                              \
        af[fi_][p_] = *(const bf16x8*)&lds[base_ + r_ * 64 + ((ch_ ^ (r_ & 7)) << 3)]; \
      }                                                                        \
    }                                                                          \
  } while (0)

// B frags for kstep S (both col-halves): bfr[qn][plane][S]
#define LOADB32(BUF, S)                                                        \
  do {                                                                         \
    _Pragma("unroll") for (int qn_ = 0; qn_ < 2; ++qn_) {                      \
      const int base_ = B_LDS(BUF, qn_);                                       \
      const int r_ = wc * 32 + ln31;                                           \
      _Pragma("unroll") for (int p_ = 0; p_ < 2; ++p_) {                       \
        const int ch_ = p_ * 4 + (S) * 2 + khalf;                              \
        bfr[qn_][p_][S] = *(const bf16x8*)&lds[base_ + r_ * 64 + ((ch_ ^ (r_ & 7)) << 3)]; \
      }                                                                        \
    }                                                                          \
  } while (0)

// 12 MFMA, term-major: (pa,pb) = (0,0),(0,1),(1,0)
#define MMAQ32(QM, S)                                                          \
  do {                                                                         \
    _Pragma("unroll") for (int t_ = 0; t_ < 3; ++t_) {                         \
      const int pa_ = (t_ == 2) ? 1 : 0;                                       \
      const int pb_ = (t_ == 1) ? 1 : 0;                                       \
      _Pragma("unroll") for (int fi_ = 0; fi_ < 2; ++fi_) {                    \
        _Pragma("unroll") for (int qn_ = 0; qn_ < 2; ++qn_) {                  \
          acc[(QM) * 2 + fi_][qn_] = __builtin_amdgcn_mfma_f32_32x32x16_bf16(  \
              af[fi_][pa_], bfr[qn_][pb_][S], acc[(QM) * 2 + fi_][qn_], 0, 0, 0); \
        }                                                                      \
      }                                                                        \
    }                                                                          \
  } while (0)

#define PH_PRE()                                                               \
  __builtin_amdgcn_s_barrier();                                                \
  asm volatile("s_waitcnt lgkmcnt(0)" ::: "memory");                           \
  __builtin_amdgcn_s_setprio(1)

#define PH_POST()                                                              \
  __builtin_amdgcn_s_setprio(0);                                               \
  __builtin_amdgcn_s_barrier()

template <int EPI>
__global__ __launch_bounds__(512, 2) void gemm8s(
    const u16* __restrict__ Ah, const u16* __restrict__ Al,
    const u16* __restrict__ Bh, const u16* __restrict__ Bl,
    const float* __restrict__ bias, float* __restrict__ Cf,
    u16* __restrict__ Ch, u16* __restrict__ Cl, int M, int N, int K,
    long long sA, long long sB, long long sC) {
  extern __shared__ u16 lds[];

  const int tt = threadIdx.x;
  const int lane = tt & 63;
  const int wv = tt >> 6;
  const int wr = wv >> 2;    // 0..1
  const int wc = wv & 3;     // 0..3
  const int ln31 = lane & 31;
  const int khalf = lane >> 5;

  const long long zb = blockIdx.z;
  const u16* pAh = Ah + zb * sA;
  const u16* pAl = Al + zb * sA;
  const u16* pBh = Bh + zb * sB;
  const u16* pBl = Bl + zb * sB;
  const int m0 = blockIdx.x * 256;
  const int n0 = blockIdx.y * 256;

  const int sr = tt >> 3;
  const int ss = tt & 7;
  const int sc = ss ^ (sr & 7);
  const int ldsW = (tt & ~63) * 8;

  f32x16 acc[4][2] = {};
  bf16x8 af[2][2], bfr[2][2][2];

  const int NT = K / 32;
  const int NITER = NT / 2;

  // prologue: tile0 full + tile1 B-halves
  STAGE(A_LDS(0, 0), pAh, pAl, m0, 0);
  STAGE(A_LDS(0, 1), pAh, pAl, m0 + 128, 0);
  STAGE(B_LDS(0, 0), pBh, pBl, n0, 0);
  STAGE(B_LDS(0, 1), pBh, pBl, n0 + 128, 0);
  STAGE(B_LDS(1, 0), pBh, pBl, n0, 32);
  STAGE(B_LDS(1, 1), pBh, pBl, n0 + 128, 32);
  asm volatile("s_waitcnt vmcnt(4)" ::: "memory");
  __builtin_amdgcn_s_barrier();
  __builtin_amdgcn_sched_barrier(0);

  for (int it = 0; it < NITER; ++it) {
    const int t0 = 2 * it;
    const int k1 = (t0 + 1) * 32;
    const int k2 = (t0 + 2 < NT ? t0 + 2 : NT - 1) * 32;
    const int k3 = (t0 + 3 < NT ? t0 + 3 : NT - 1) * 32;

    // P1: (qm0,s0) buf0 | stage A(1,h0) <- t1
    LOADA32(0, 0, 0);
    LOADB32(0, 0);
    STAGE(A_LDS(1, 0), pAh, pAl, m0, k1);
    PH_PRE();
    MMAQ32(0, 0);
    PH_POST();

    // P2: (qm1,s0) buf0 | preload B s1 | stage A(1,h1) <- t1
    LOADA32(0, 1, 0);
    LOADB32(0, 1);
    STAGE(A_LDS(1, 1), pAh, pAl, m0 + 128, k1);
    PH_PRE();
    MMAQ32(1, 0);
    PH_POST();

    // P3: (qm0,s1) buf0 | stage B(0,h0) <- t2
    LOADA32(0, 0, 1);
    STAGE(B_LDS(0, 0), pBh, pBl, n0, k2);
    PH_PRE();
    MMAQ32(0, 1);
    PH_POST();

    // P4: (qm1,s1) buf0 | stage B(0,h1) <- t2 | vmcnt(4)
    LOADA32(0, 1, 1);
    STAGE(B_LDS(0, 1), pBh, pBl, n0 + 128, k2);
    __builtin_amdgcn_s_barrier();
    asm volatile("s_waitcnt lgkmcnt(0)" ::: "memory");
    __builtin_amdgcn_s_setprio(1);
    MMAQ32(1, 1);
    __builtin_amdgcn_s_setprio(0);
    asm volatile("s_waitcnt vmcnt(4)" ::: "memory");
    __builtin_amdgcn_s_barrier();
    __builtin_amdgcn_sched_barrier(0);

    // P5: (qm0,s0) buf1 | stage A(0,h0) <- t2
    LOADA32(1, 0, 0);
    LOADB32(1, 0);
    STAGE(A_LDS(0, 0), pAh, pAl, m0, k2);
    PH_PRE();
    MMAQ32(0, 0);
    PH_POST();

    // P6: (qm1,s0) buf1 | preload B s1 | stage A(0,h1) <- t2
    LOADA32(1, 1, 0);
    LOADB32(1, 1);
    STAGE(A_LDS(0, 1), pAh, pAl, m0 + 128, k2);
    PH_PRE();
    MMAQ32(1, 0);
    PH_POST();

    // P7: (qm0,s1) buf1 | stage B(1,h0) <- t3
    LOADA32(1, 0, 1);
    STAGE(B_LDS(1, 0), pBh, pBl, n0, k3);
    PH_PRE();
    MMAQ32(0, 1);
    PH_POST();

    // P8: (qm1,s1) buf1 | stage B(1,h1) <- t3 | vmcnt(4)
    LOADA32(1, 1, 1);
    STAGE(B_LDS(1, 1), pBh, pBl, n0 + 128, k3);
    __builtin_amdgcn_s_barrier();
    asm volatile("s_waitcnt lgkmcnt(0)" ::: "memory");
    __builtin_amdgcn_s_setprio(1);
    MMAQ32(1, 1);
    __builtin_amdgcn_s_setprio(0);
    asm volatile("s_waitcnt vmcnt(4)" ::: "memory");
    __builtin_amdgcn_s_barrier();
    __builtin_amdgcn_sched_barrier(0);
  }

  // epilogue: 32x32 C/D map: col = lane&31, row = (reg&3)+8*(reg>>2)+4*(lane>>5)
#pragma unroll
  for (int fg = 0; fg < 4; ++fg) {
    const int qm = fg >> 1, fi = fg & 1;
    const int rbase = m0 + qm * 128 + wr * 64 + fi * 32 + 4 * khalf;
#pragma unroll
    for (int qn = 0; qn < 2; ++qn) {
      const int gcol = n0 + qn * 128 + wc * 32 + ln31;
      const float bv = bias ? bias[gcol] : 0.0f;
#pragma unroll
      for (int r = 0; r < 16; ++r) {
        const int grow = rbase + (r & 3) + 8 * (r >> 2);
        const float x = acc[fg][qn][r] + bv;
        const size_t off = (size_t)zb * sC + (size_t)grow * N + gcol;
        if constexpr (EPI == 0) {
          Cf[off] = x;
        } else {
          const u16 h = f2bf(x);
          Ch[off] = h;
          Cl[off] = f2bf(x - bf2f(h));
        }
      }
    }
  }
}

// ---------------------------------------------------------------------------
// Row softmax: in-place fp32 (weights output) + bf16 copy (P for PV GEMM).
// ---------------------------------------------------------------------------
__global__ __launch_bounds__(256) void softmax_rows(float* __restrict__ S,
                                                    u16* __restrict__ P) {
  const int T = 2048;
  const size_t row = blockIdx.x;
  float* sr = S + row * T;
  u16* pr = P + row * T;
  const int t = threadIdx.x;
  const int w = t >> 6, lane = t & 63;
  __shared__ float red[8];

  float v[8];
  float mx = -1e30f;
#pragma unroll
  for (int i = 0; i < 8; ++i) {
    v[i] = sr[t + 256 * i];
    mx = fmaxf(mx, v[i]);
  }
#pragma unroll
  for (int off = 32; off; off >>= 1) mx = fmaxf(mx, __shfl_xor(mx, off));
  if (lane == 0) red[w] = mx;
  __syncthreads();
  mx = fmaxf(fmaxf(red[0], red[1]), fmaxf(red[2], red[3]));

  float s = 0.f;
#pragma unroll
  for (int i = 0; i < 8; ++i) {
    v[i] = __expf(v[i] - mx);
    s += v[i];
  }
#pragma unroll
  for (int off = 32; off; off >>= 1) s += __shfl_xor(s, off);
  if (lane == 0) red[4 + w] = s;
  __syncthreads();
  s = (red[4] + red[5]) + (red[6] + red[7]);
  const float inv = 1.0f / s;
#pragma unroll
  for (int i = 0; i < 8; ++i) {
    const float wv = v[i] * inv;
    sr[t + 256 * i] = wv;
    pr[t + 256 * i] = f2bf(wv);
  }
}

// ---------------------------------------------------------------------------
extern "C" void kernel_launch(void* const* d_in, const int* in_sizes, int n_in,
                              void* d_out, int out_size, void* d_ws,
                              size_t ws_size, hipStream_t stream) {
  (void)in_sizes; (void)n_in; (void)out_size; (void)ws_size;
  const float* query = (const float*)d_in[0];
  const float* key   = (const float*)d_in[1];
  const float* value = (const float*)d_in[2];
  const float* Wq    = (const float*)d_in[3];
  const float* bq    = (const float*)d_in[4];
  const float* Wo    = (const float*)d_in[5];
  const float* bo    = (const float*)d_in[6];

  const int S = 2048, D = 1024;
  const size_t n = (size_t)4 * S * D;  // 8,388,608

  float* out = (float*)d_out;          // (B,S,D) f32, 32MB
  float* wts = out + n;                // (B,S,T) f32, 64MB

  char* ws = (char*)d_ws;
  u16* wqt_h = (u16*)(ws);                   // 2MB  Wq^T hi
  u16* wqt_l = (u16*)(ws + (2ull << 20));    // 2MB  Wq^T lo
  u16* wot   = (u16*)(ws + (4ull << 20));    // 2MB  Wo^T bf16
  u16* wq_b  = (u16*)(ws + (6ull << 20));    // 2MB  Wq bf16 row-major
  u16* wqoT  = (u16*)(ws + (8ull << 20));    // 2MB  (Wq@Wo)^T bf16
  float* bqo = (float*)(ws + (10ull << 20)); // 4KB
  u16* QKh   = (u16*)(ws + (12ull << 20));   // 32MB: Q rows then K rows
  u16* QKl   = (u16*)(ws + (44ull << 20));   // 32MB  (total ws: 76MB)
  u16* P   = QKh;  // 32MB (QKh dead after score GEMM)
  u16* tmp = QKl;  // 16MB (QKl dead after score GEMM); tmp = P@value^T

  // scratch in d_out: wts region holds input splits until score GEMM writes;
  // out region holds value^T until the final GEMM writes.
  u16* qkin_h = (u16*)wts;  // [q(8192 rows); k(8192 rows)]
  u16* qkin_l = qkin_h + 2 * n;
  u16* valT = (u16*)out;    // (B, D, T) bf16, 16MB

  hipFuncSetAttribute((const void*)&gemm8s<2>,
                      hipFuncAttributeMaxDynamicSharedMemorySize, 131072);
  hipFuncSetAttribute((const void*)&gemm8s<0>,
                      hipFuncAttributeMaxDynamicSharedMemorySize, 131072);

  // 1. split q,k inputs (stacked)
  split_qk<<<2048, 256, 0, stream>>>(query, key, qkin_h, qkin_l, qkin_h + n,
                                     qkin_l + n, (int)(n / 4));
  // 2. weight prep
  prep_w_t<<<dim3(D / 32, D / 32), dim3(32, 8), 0, stream>>>(
      Wq, Wo, wqt_h, wqt_l, wot, wq_b, D);
  // 3. value^T (f32 -> bf16), per batch
  transpose_f32_bf16<<<dim3(D / 32, S / 32, 4), dim3(32, 8), 0, stream>>>(
      value, valT, S, D);
  // 4. WqoT[f][e] = sum_d Wo^T[f][d] * Wq[e][d]   (= (Wq@Wo)^T)
  gemm_bt<1><<<dim3(8, 8, 1), 256, 0, stream>>>(
      wot, wq_b, nullptr, nullptr, wqoT, 1024, 1024, 1024, 0, 0, 0);
  // 5. bqo = bq@Wo + bo  (wave-per-f GEMV over wot; 1024 waves)
  bqo_kernel<<<256, 256, 0, stream>>>(bq, wot, bo, bqo, D);
  // 6. [Q;K] = [q;k] @ Wq + bq  (split in, split out) — 8-phase 256^2
  gemm8s<2><<<dim3(64, 4, 1), 512, 131072, stream>>>(
      qkin_h, qkin_l, wqt_h, wqt_l, bq, nullptr, QKh, QKl, 16384, 1024, 1024,
      0, 0, 0);
  // 7. score = Q @ K^T (split, fp32 out into weights region) — 8-phase 256^2
  gemm8s<0><<<dim3(8, 8, 4), 512, 131072, stream>>>(
      QKh, QKl, QKh + n, QKl + n, nullptr, wts, nullptr, nullptr, 2048, 2048,
      1024, (long long)S * D, (long long)S * D, (long long)S * S);
  // 8. softmax rows (in-place) + bf16 P
  softmax_rows<<<8192, 256, 0, stream>>>(wts, P);
  // 9. tmp = P @ value^T   (Bt = valT, K-major)
  gemm_bt<1><<<dim3(16, 8, 4), 256, 0, stream>>>(
      P, valT, nullptr, nullptr, tmp, 2048, 1024, 2048, (long long)S * S,
      (long long)D * S, (long long)S * D);
  // 10. out = tmp @ Wqo + bqo   (Bt = WqoT)
  gemm_bt<0><<<dim3(64, 8, 1), 256, 0, stream>>>(
      tmp, wqoT, bqo, out, nullptr, 8192, 1024, 1024, 0, 0, 0);
}

// Round 5
// 351.073 us; speedup vs baseline: 1.7204x; 1.0555x over previous
//
#include <hip/hip_runtime.h>

typedef unsigned short u16;
typedef unsigned int u32;
typedef __bf16 bf16x8 __attribute__((ext_vector_type(8)));
typedef float f32x4 __attribute__((ext_vector_type(4)));
typedef unsigned short u16x4 __attribute__((ext_vector_type(4)));

#define AS1(p) ((const __attribute__((address_space(1))) void*)(p))
#define AS3(p) ((__attribute__((address_space(3))) void*)(p))

__device__ __forceinline__ u16 f2bf(float x) {
  u32 u = __float_as_uint(x);
  u32 r = u + 0x7fffu + ((u >> 16) & 1u);
  return (u16)(r >> 16);
}
__device__ __forceinline__ float bf2f(u16 h) {
  return __uint_as_float(((u32)h) << 16);
}

// ---------------------------------------------------------------------------
// split fp32 -> (bf16 hi, bf16 lo) for q and k.
// ---------------------------------------------------------------------------
__device__ __forceinline__ void split4(float4 x, u16x4& h, u16x4& l) {
  float xs[4] = {x.x, x.y, x.z, x.w};
#pragma unroll
  for (int e = 0; e < 4; ++e) {
    u16 hh = f2bf(xs[e]);
    h[e] = hh;
    l[e] = f2bf(xs[e] - bf2f(hh));
  }
}

__global__ __launch_bounds__(256) void split_qk(
    const float* __restrict__ q, const float* __restrict__ k,
    u16* __restrict__ qh, u16* __restrict__ ql, u16* __restrict__ kh,
    u16* __restrict__ kl, int n4) {
  int stride = gridDim.x * blockDim.x;
  for (int i = blockIdx.x * blockDim.x + threadIdx.x; i < n4; i += stride) {
    u16x4 h, l;
    float4 x = ((const float4*)q)[i];
    split4(x, h, l);
    ((u16x4*)qh)[i] = h;
    ((u16x4*)ql)[i] = l;
    x = ((const float4*)k)[i];
    split4(x, h, l);
    ((u16x4*)kh)[i] = h;
    ((u16x4*)kl)[i] = l;
  }
}

// Weight prep: wqt = split(Wq^T); wot = bf16(Wo^T); wq_b = bf16(Wq) row-major.
__global__ void prep_w_t(const float* __restrict__ Wq,
                         const float* __restrict__ Wo, u16* __restrict__ wqt_h,
                         u16* __restrict__ wqt_l, u16* __restrict__ wot,
                         u16* __restrict__ wq_b, int D) {
  __shared__ float tq[32][33];
  __shared__ float to[32][33];
  int c0 = blockIdx.x * 32, r0 = blockIdx.y * 32;
  int tx = threadIdx.x, ty = threadIdx.y;
#pragma unroll
  for (int i = ty; i < 32; i += 8) {
    float xq = Wq[(size_t)(r0 + i) * D + c0 + tx];
    tq[i][tx] = xq;
    wq_b[(size_t)(r0 + i) * D + c0 + tx] = f2bf(xq);
    to[i][tx] = Wo[(size_t)(r0 + i) * D + c0 + tx];
  }
  __syncthreads();
#pragma unroll
  for (int i = ty; i < 32; i += 8) {
    float x = tq[tx][i];  // = Wq[(r0+tx)][c0+i]
    u16 h = f2bf(x);
    size_t o = (size_t)(c0 + i) * D + r0 + tx;
    wqt_h[o] = h;
    wqt_l[o] = f2bf(x - bf2f(h));
    wot[o] = f2bf(to[tx][i]);
  }
}

// Batched transpose f32 -> bf16: out[z][c][r] = bf16(in[z][r][c])
__global__ void transpose_f32_bf16(const float* __restrict__ in,
                                   u16* __restrict__ out, int R, int C) {
  __shared__ float tile[32][33];
  size_t zi = (size_t)blockIdx.z * R * C;
  int c0 = blockIdx.x * 32, r0 = blockIdx.y * 32;
  int tx = threadIdx.x, ty = threadIdx.y;
#pragma unroll
  for (int i = ty; i < 32; i += 8)
    tile[i][tx] = in[zi + (size_t)(r0 + i) * C + (c0 + tx)];
  __syncthreads();
#pragma unroll
  for (int i = ty; i < 32; i += 8)
    out[zi + (size_t)(c0 + i) * R + (r0 + tx)] = f2bf(tile[tx][i]);
}

// bqo[f] = sum_e bq[e]*Wo[e][f] + bo[f]   via wot (Wo^T bf16, row-contiguous).
__global__ __launch_bounds__(256) void bqo_kernel(const float* __restrict__ bq,
                                                  const u16* __restrict__ wot,
                                                  const float* __restrict__ bo,
                                                  float* __restrict__ bqo,
                                                  int D) {
  const int f = blockIdx.x * 4 + (threadIdx.x >> 6);
  const int lane = threadIdx.x & 63;
  const u16* wr_ = wot + (size_t)f * D;
  float s = 0.f;
  for (int e = lane; e < D; e += 64) s += bq[e] * bf2f(wr_[e]);
#pragma unroll
  for (int off = 32; off; off >>= 1) s += __shfl_xor(s, off);
  if (lane == 0) bqo[f] = s + bo[f];
}

// ---------------------------------------------------------------------------
// 128x128 2-barrier GEMM for the small plain GEMMs (Wqo / PV / outproj).
// C[m][n] = sum_k A[m][k]*Bt[n][k] (+bias); EPI: 0=f32, 1=bf16.
// ---------------------------------------------------------------------------
template <int EPI>
__global__ __launch_bounds__(256, 2) void gemm_bt(
    const u16* __restrict__ Ah, const u16* __restrict__ Bh,
    const float* __restrict__ bias, float* __restrict__ Cf,
    u16* __restrict__ Ch, int M, int N, int K,
    long long sA, long long sB, long long sC) {
  __shared__ alignas(16) u16 As[128 * 32];
  __shared__ alignas(16) u16 Bs[128 * 32];

  const int t = threadIdx.x;
  const int lane = t & 63;
  const int w = t >> 6;
  const int wr = w >> 1, wc = w & 1;

  const long long zb = blockIdx.z;
  const u16* pA = Ah + zb * sA;
  const u16* pB = Bh + zb * sB;

  const int m0 = blockIdx.x * 128;
  const int n0 = blockIdx.y * 128;

  f32x4 acc[4][4] = {};

  const int row0 = t >> 2;
  const int colS = (t & 3) * 8;
  const int lds0 = (t & ~63) * 8;
  const int lds1 = (256 + (t & ~63)) * 8;

  const size_t aoff0 = (size_t)(m0 + row0) * K + colS;
  const size_t aoff1 = (size_t)(m0 + row0 + 64) * K + colS;
  const size_t boff0 = (size_t)(n0 + row0) * K + colS;
  const size_t boff1 = (size_t)(n0 + row0 + 64) * K + colS;

  for (int k0 = 0; k0 < K; k0 += 32) {
    __syncthreads();
    __builtin_amdgcn_global_load_lds(AS1(pA + aoff0 + k0), AS3(&As[lds0]), 16, 0, 0);
    __builtin_amdgcn_global_load_lds(AS1(pA + aoff1 + k0), AS3(&As[lds1]), 16, 0, 0);
    __builtin_amdgcn_global_load_lds(AS1(pB + boff0 + k0), AS3(&Bs[lds0]), 16, 0, 0);
    __builtin_amdgcn_global_load_lds(AS1(pB + boff1 + k0), AS3(&Bs[lds1]), 16, 0, 0);
    __syncthreads();

    const int fr = lane & 15;
    const int kc = (lane >> 4) * 8;
    bf16x8 a[4], b[4];
#pragma unroll
    for (int i = 0; i < 4; ++i)
      a[i] = *(const bf16x8*)&As[(wr * 64 + i * 16 + fr) * 32 + kc];
#pragma unroll
    for (int j = 0; j < 4; ++j)
      b[j] = *(const bf16x8*)&Bs[(wc * 64 + j * 16 + fr) * 32 + kc];
#pragma unroll
    for (int i = 0; i < 4; ++i)
#pragma unroll
      for (int j = 0; j < 4; ++j)
        acc[i][j] = __builtin_amdgcn_mfma_f32_16x16x32_bf16(a[i], b[j], acc[i][j], 0, 0, 0);
  }

  const int er = (lane >> 4) * 4;
  const int ec = lane & 15;
#pragma unroll
  for (int j = 0; j < 4; ++j) {
    const int gcol = n0 + wc * 64 + j * 16 + ec;
    const float bv = bias ? bias[gcol] : 0.0f;
#pragma unroll
    for (int i = 0; i < 4; ++i) {
      const int grow0 = m0 + wr * 64 + i * 16 + er;
#pragma unroll
      for (int r = 0; r < 4; ++r) {
        const float x = acc[i][j][r] + bv;
        const size_t off = (size_t)zb * sC + (size_t)(grow0 + r) * N + gcol;
        if constexpr (EPI == 0) Cf[off] = x;
        else Ch[off] = f2bf(x);
      }
    }
  }
}

// ---------------------------------------------------------------------------
// 256x256 8-phase split GEMM (Markidis 3-term), BK=32 real K per tile packed
// as 64 virtual-K (hi chunks 0-3, lo chunks 4-7). 512 threads (8 waves, 2x4),
// 128 KiB dynamic LDS (double-buffered), XOR-swizzled LDS, counted vmcnt(4),
// setprio around MFMA clusters. EPI: 0 = f32 out, 2 = bf16 hi/lo split out.
// 16x16x32 MFMA variant — measured 0 bank conflicts (round 2).
// ---------------------------------------------------------------------------
#define A_LDS(BUF, H) ((BUF) * 32768 + (H) * 8192)
#define B_LDS(BUF, H) ((BUF) * 32768 + 16384 + (H) * 8192)

#define STAGE(DSTBASE, SH, SL, ROWBASE, KREAL)                                 \
  do {                                                                         \
    const u16* s0_ = (sc < 4 ? (SH) : (SL)) +                                  \
                     (size_t)((ROWBASE) + sr) * K + (KREAL) + ((sc & 3) << 3); \
    const u16* s1_ = s0_ + (size_t)64 * K;                                     \
    __builtin_amdgcn_global_load_lds(AS1(s0_), AS3(&lds[(DSTBASE) + ldsW]), 16, 0, 0); \
    __builtin_amdgcn_global_load_lds(AS1(s1_), AS3(&lds[(DSTBASE) + 4096 + ldsW]), 16, 0, 0); \
  } while (0)

#define LOADA(BUF, QM)                                                         \
  do {                                                                         \
    const int base_ = A_LDS(BUF, QM);                                          \
    _Pragma("unroll") for (int i_ = 0; i_ < 4; ++i_) {                         \
      const int r_ = wr * 64 + i_ * 16 + fr;                                   \
      const int sw_ = r_ & 7;                                                  \
      aH[i_] = *(const bf16x8*)&lds[base_ + r_ * 64 + ((ksl ^ sw_) << 3)];     \
      aL[i_] = *(const bf16x8*)&lds[base_ + r_ * 64 + (((4 + ksl) ^ sw_) << 3)]; \
    }                                                                          \
  } while (0)

#define LOADB(BUF, QN, BH, BL)                                                 \
  do {                                                                         \
    const int base_ = B_LDS(BUF, QN);                                          \
    _Pragma("unroll") for (int j_ = 0; j_ < 2; ++j_) {                         \
      const int r_ = wc * 32 + j_ * 16 + fr;                                   \
      const int sw_ = r_ & 7;                                                  \
      BH[j_] = *(const bf16x8*)&lds[base_ + r_ * 64 + ((ksl ^ sw_) << 3)];     \
      BL[j_] = *(const bf16x8*)&lds[base_ + r_ * 64 + (((4 + ksl) ^ sw_) << 3)]; \
    }                                                                          \
  } while (0)

#define MMAQ(QM, QN, BH, BL)                                                   \
  do {                                                                         \
    _Pragma("unroll") for (int i_ = 0; i_ < 4; ++i_) {                         \
      _Pragma("unroll") for (int j_ = 0; j_ < 2; ++j_) {                       \
        f32x4 c_ = acc[(QM) * 4 + i_][(QN) * 2 + j_];                          \
        c_ = __builtin_amdgcn_mfma_f32_16x16x32_bf16(aH[i_], BH[j_], c_, 0, 0, 0); \
        c_ = __builtin_amdgcn_mfma_f32_16x16x32_bf16(aH[i_], BL[j_], c_, 0, 0, 0); \
        c_ = __builtin_amdgcn_mfma_f32_16x16x32_bf16(aL[i_], BH[j_], c_, 0, 0, 0); \
        acc[(QM) * 4 + i_][(QN) * 2 + j_] = c_;                                \
      }                                                                        \
    }                                                                          \
  } while (0)

#define PH_PRE()                                                               \
  __builtin_amdgcn_s_barrier();                                                \
  asm volatile("s_waitcnt lgkmcnt(0)" ::: "memory");                           \
  __builtin_amdgcn_s_setprio(1)

#define PH_POST()                                                              \
  __builtin_amdgcn_s_setprio(0);                                               \
  __builtin_amdgcn_s_barrier()

template <int EPI>
__global__ __launch_bounds__(512, 2) void gemm8s(
    const u16* __restrict__ Ah, const u16* __restrict__ Al,
    const u16* __restrict__ Bh, const u16* __restrict__ Bl,
    const float* __restrict__ bias, float* __restrict__ Cf,
    u16* __restrict__ Ch, u16* __restrict__ Cl, int M, int N, int K,
    long long sA, long long sB, long long sC) {
  extern __shared__ u16 lds[];

  const int tt = threadIdx.x;
  const int lane = tt & 63;
  const int wv = tt >> 6;
  const int wr = wv >> 2;  // 0..1
  const int wc = wv & 3;   // 0..3
  const int fr = lane & 15;
  const int ksl = lane >> 4;  // 0..3

  const long long zb = blockIdx.z;
  const u16* pAh = Ah + zb * sA;
  const u16* pAl = Al + zb * sA;
  const u16* pBh = Bh + zb * sB;
  const u16* pBl = Bl + zb * sB;
  const int m0 = blockIdx.x * 256;
  const int n0 = blockIdx.y * 256;

  const int sr = tt >> 3;
  const int ss = tt & 7;
  const int sc = ss ^ (sr & 7);
  const int ldsW = (tt & ~63) * 8;

  f32x4 acc[8][4] = {};
  bf16x8 aH[4], aL[4], bH0[2], bL0[2], bH1[2], bL1[2];

  const int NT = K / 32;
  const int NITER = NT / 2;

  // prologue: tile0 full + tile1 halves0
  STAGE(A_LDS(0, 0), pAh, pAl, m0, 0);
  STAGE(B_LDS(0, 0), pBh, pBl, n0, 0);
  STAGE(A_LDS(0, 1), pAh, pAl, m0 + 128, 0);
  STAGE(B_LDS(0, 1), pBh, pBl, n0 + 128, 0);
  STAGE(A_LDS(1, 0), pAh, pAl, m0, 32);
  STAGE(B_LDS(1, 0), pBh, pBl, n0, 32);
  asm volatile("s_waitcnt vmcnt(4)" ::: "memory");
  __builtin_amdgcn_s_barrier();
  __builtin_amdgcn_sched_barrier(0);

  for (int it = 0; it < NITER; ++it) {
    const int t0 = 2 * it;
    const int k1 = (t0 + 1) * 32;
    const int k2 = (t0 + 2 < NT ? t0 + 2 : NT - 1) * 32;
    const int k3 = (t0 + 3 < NT ? t0 + 3 : NT - 1) * 32;

    // P1: quad(0,0) buf0 | stage A(1,h1) <- t1
    LOADA(0, 0);
    LOADB(0, 0, bH0, bL0);
    STAGE(A_LDS(1, 1), pAh, pAl, m0 + 128, k1);
    PH_PRE();
    MMAQ(0, 0, bH0, bL0);
    PH_POST();

    // P2: quad(0,1) buf0 | stage B(1,h1) <- t1
    LOADB(0, 1, bH1, bL1);
    STAGE(B_LDS(1, 1), pBh, pBl, n0 + 128, k1);
    PH_PRE();
    MMAQ(0, 1, bH1, bL1);
    PH_POST();

    // P3: quad(1,0) buf0 | stage A(0,h0) <- t2
    LOADA(0, 1);
    STAGE(A_LDS(0, 0), pAh, pAl, m0, k2);
    PH_PRE();
    MMAQ(1, 0, bH0, bL0);
    PH_POST();

    // P4: quad(1,1) buf0 | stage B(0,h0) <- t2 | vmcnt(4)
    STAGE(B_LDS(0, 0), pBh, pBl, n0, k2);
    __builtin_amdgcn_s_barrier();
    asm volatile("s_waitcnt lgkmcnt(0)" ::: "memory");
    __builtin_amdgcn_s_setprio(1);
    MMAQ(1, 1, bH1, bL1);
    __builtin_amdgcn_s_setprio(0);
    asm volatile("s_waitcnt vmcnt(4)" ::: "memory");
    __builtin_amdgcn_s_barrier();
    __builtin_amdgcn_sched_barrier(0);

    // P5: quad(0,0) buf1 | stage A(0,h1) <- t2
    LOADA(1, 0);
    LOADB(1, 0, bH0, bL0);
    STAGE(A_LDS(0, 1), pAh, pAl, m0 + 128, k2);
    PH_PRE();
    MMAQ(0, 0, bH0, bL0);
    PH_POST();

    // P6: quad(0,1) buf1 | stage B(0,h1) <- t2
    LOADB(1, 1, bH1, bL1);
    STAGE(B_LDS(0, 1), pBh, pBl, n0 + 128, k2);
    PH_PRE();
    MMAQ(0, 1, bH1, bL1);
    PH_POST();

    // P7: quad(1,0) buf1 | stage B(1,h0) <- t3
    LOADA(1, 1);
    STAGE(B_LDS(1, 0), pBh, pBl, n0, k3);
    PH_PRE();
    MMAQ(1, 0, bH0, bL0);
    PH_POST();

    // P8: quad(1,1) buf1 | stage A(1,h0) <- t3 | vmcnt(4)
    STAGE(A_LDS(1, 0), pAh, pAl, m0, k3);
    __builtin_amdgcn_s_barrier();
    asm volatile("s_waitcnt lgkmcnt(0)" ::: "memory");
    __builtin_amdgcn_s_setprio(1);
    MMAQ(1, 1, bH1, bL1);
    __builtin_amdgcn_s_setprio(0);
    asm volatile("s_waitcnt vmcnt(4)" ::: "memory");
    __builtin_amdgcn_s_barrier();
    __builtin_amdgcn_sched_barrier(0);
  }

  // epilogue: C/D map col=lane&15, row=(lane>>4)*4+reg
  const int er = (lane >> 4) * 4;
  const int ec = lane & 15;
#pragma unroll
  for (int fi = 0; fi < 8; ++fi) {
    const int qm = fi >> 2, i = fi & 3;
    const int grow0 = m0 + qm * 128 + wr * 64 + i * 16 + er;
#pragma unroll
    for (int fj = 0; fj < 4; ++fj) {
      const int qn = fj >> 1, j = fj & 1;
      const int gcol = n0 + qn * 128 + wc * 32 + j * 16 + ec;
      const float bv = bias ? bias[gcol] : 0.0f;
#pragma unroll
      for (int r = 0; r < 4; ++r) {
        const float x = acc[fi][fj][r] + bv;
        const size_t off = (size_t)zb * sC + (size_t)(grow0 + r) * N + gcol;
        if constexpr (EPI == 0) {
          Cf[off] = x;
        } else {
          const u16 h = f2bf(x);
          Ch[off] = h;
          Cl[off] = f2bf(x - bf2f(h));
        }
      }
    }
  }
}

// ---------------------------------------------------------------------------
// Row softmax: in-place fp32 (weights output) + bf16 copy (P for PV GEMM).
// ---------------------------------------------------------------------------
__global__ __launch_bounds__(256) void softmax_rows(float* __restrict__ S,
                                                    u16* __restrict__ P) {
  const int T = 2048;
  const size_t row = blockIdx.x;
  float* sr = S + row * T;
  u16* pr = P + row * T;
  const int t = threadIdx.x;
  const int w = t >> 6, lane = t & 63;
  __shared__ float red[8];

  float v[8];
  float mx = -1e30f;
#pragma unroll
  for (int i = 0; i < 8; ++i) {
    v[i] = sr[t + 256 * i];
    mx = fmaxf(mx, v[i]);
  }
#pragma unroll
  for (int off = 32; off; off >>= 1) mx = fmaxf(mx, __shfl_xor(mx, off));
  if (lane == 0) red[w] = mx;
  __syncthreads();
  mx = fmaxf(fmaxf(red[0], red[1]), fmaxf(red[2], red[3]));

  float s = 0.f;
#pragma unroll
  for (int i = 0; i < 8; ++i) {
    v[i] = __expf(v[i] - mx);
    s += v[i];
  }
#pragma unroll
  for (int off = 32; off; off >>= 1) s += __shfl_xor(s, off);
  if (lane == 0) red[4 + w] = s;
  __syncthreads();
  s = (red[4] + red[5]) + (red[6] + red[7]);
  const float inv = 1.0f / s;
#pragma unroll
  for (int i = 0; i < 8; ++i) {
    const float wv = v[i] * inv;
    sr[t + 256 * i] = wv;
    pr[t + 256 * i] = f2bf(wv);
  }
}

// ---------------------------------------------------------------------------
extern "C" void kernel_launch(void* const* d_in, const int* in_sizes, int n_in,
                              void* d_out, int out_size, void* d_ws,
                              size_t ws_size, hipStream_t stream) {
  (void)in_sizes; (void)n_in; (void)out_size; (void)ws_size;
  const float* query = (const float*)d_in[0];
  const float* key   = (const float*)d_in[1];
  const float* value = (const float*)d_in[2];
  const float* Wq    = (const float*)d_in[3];
  const float* bq    = (const float*)d_in[4];
  const float* Wo    = (const float*)d_in[5];
  const float* bo    = (const float*)d_in[6];

  const int S = 2048, D = 1024;
  const size_t n = (size_t)4 * S * D;  // 8,388,608

  float* out = (float*)d_out;          // (B,S,D) f32, 32MB
  float* wts = out + n;                // (B,S,T) f32, 64MB

  char* ws = (char*)d_ws;
  u16* wqt_h = (u16*)(ws);                   // 2MB  Wq^T hi
  u16* wqt_l = (u16*)(ws + (2ull << 20));    // 2MB  Wq^T lo
  u16* wot   = (u16*)(ws + (4ull << 20));    // 2MB  Wo^T bf16
  u16* wq_b  = (u16*)(ws + (6ull << 20));    // 2MB  Wq bf16 row-major
  u16* wqoT  = (u16*)(ws + (8ull << 20));    // 2MB  (Wq@Wo)^T bf16
  float* bqo = (float*)(ws + (10ull << 20)); // 4KB
  u16* QKh   = (u16*)(ws + (12ull << 20));   // 32MB: Q rows then K rows
  u16* QKl   = (u16*)(ws + (44ull << 20));   // 32MB  (total ws: 76MB)
  u16* P   = QKh;  // 32MB (QKh dead after score GEMM)
  u16* tmp = QKl;  // 16MB (QKl dead after score GEMM); tmp = P@value^T

  // scratch in d_out: wts region holds input splits until score GEMM writes;
  // out region holds value^T until the final GEMM writes.
  u16* qkin_h = (u16*)wts;  // [q(8192 rows); k(8192 rows)]
  u16* qkin_l = qkin_h + 2 * n;
  u16* valT = (u16*)out;    // (B, D, T) bf16, 16MB

  hipFuncSetAttribute((const void*)&gemm8s<2>,
                      hipFuncAttributeMaxDynamicSharedMemorySize, 131072);
  hipFuncSetAttribute((const void*)&gemm8s<0>,
                      hipFuncAttributeMaxDynamicSharedMemorySize, 131072);

  // 1. split q,k inputs (stacked)
  split_qk<<<2048, 256, 0, stream>>>(query, key, qkin_h, qkin_l, qkin_h + n,
                                     qkin_l + n, (int)(n / 4));
  // 2. weight prep
  prep_w_t<<<dim3(D / 32, D / 32), dim3(32, 8), 0, stream>>>(
      Wq, Wo, wqt_h, wqt_l, wot, wq_b, D);
  // 3. value^T (f32 -> bf16), per batch
  transpose_f32_bf16<<<dim3(D / 32, S / 32, 4), dim3(32, 8), 0, stream>>>(
      value, valT, S, D);
  // 4. WqoT[f][e] = sum_d Wo^T[f][d] * Wq[e][d]   (= (Wq@Wo)^T)
  gemm_bt<1><<<dim3(8, 8, 1), 256, 0, stream>>>(
      wot, wq_b, nullptr, nullptr, wqoT, 1024, 1024, 1024, 0, 0, 0);
  // 5. bqo = bq@Wo + bo  (wave-per-f GEMV over wot; 1024 waves)
  bqo_kernel<<<256, 256, 0, stream>>>(bq, wot, bo, bqo, D);
  // 6. [Q;K] = [q;k] @ Wq + bq  (split in, split out) — 8-phase 256^2
  gemm8s<2><<<dim3(64, 4, 1), 512, 131072, stream>>>(
      qkin_h, qkin_l, wqt_h, wqt_l, bq, nullptr, QKh, QKl, 16384, 1024, 1024,
      0, 0, 0);
  // 7. score = Q @ K^T (split, fp32 out into weights region) — 8-phase 256^2
  gemm8s<0><<<dim3(8, 8, 4), 512, 131072, stream>>>(
      QKh, QKl, QKh + n, QKl + n, nullptr, wts, nullptr, nullptr, 2048, 2048,
      1024, (long long)S * D, (long long)S * D, (long long)S * S);
  // 8. softmax rows (in-place) + bf16 P
  softmax_rows<<<8192, 256, 0, stream>>>(wts, P);
  // 9. tmp = P @ value^T   (Bt = valT, K-major)
  gemm_bt<1><<<dim3(16, 8, 4), 256, 0, stream>>>(
      P, valT, nullptr, nullptr, tmp, 2048, 1024, 2048, (long long)S * S,
      (long long)D * S, (long long)S * D);
  // 10. out = tmp @ Wqo + bqo   (Bt = WqoT)
  gemm_bt<0><<<dim3(64, 8, 1), 256, 0, stream>>>(
      tmp, wqoT, bqo, out, nullptr, 8192, 1024, 1024, 0, 0, 0);
}

// Round 6
// 335.095 us; speedup vs baseline: 1.8024x; 1.0477x over previous
//
#include <hip/hip_runtime.h>

typedef unsigned short u16;
typedef unsigned int u32;
typedef __bf16 bf16x8 __attribute__((ext_vector_type(8)));
typedef float f32x4 __attribute__((ext_vector_type(4)));
typedef unsigned short u16x4 __attribute__((ext_vector_type(4)));

#define AS1(p) ((const __attribute__((address_space(1))) void*)(p))
#define AS3(p) ((__attribute__((address_space(3))) void*)(p))

__device__ __forceinline__ u16 f2bf(float x) {
  u32 u = __float_as_uint(x);
  u32 r = u + 0x7fffu + ((u >> 16) & 1u);
  return (u16)(r >> 16);
}
__device__ __forceinline__ float bf2f(u16 h) {
  return __uint_as_float(((u32)h) << 16);
}

// ---------------------------------------------------------------------------
// split fp32 -> (bf16 hi, bf16 lo) for q and k.
// ---------------------------------------------------------------------------
__device__ __forceinline__ void split4(float4 x, u16x4& h, u16x4& l) {
  float xs[4] = {x.x, x.y, x.z, x.w};
#pragma unroll
  for (int e = 0; e < 4; ++e) {
    u16 hh = f2bf(xs[e]);
    h[e] = hh;
    l[e] = f2bf(xs[e] - bf2f(hh));
  }
}

__global__ __launch_bounds__(256) void split_qk(
    const float* __restrict__ q, const float* __restrict__ k,
    u16* __restrict__ qh, u16* __restrict__ ql, u16* __restrict__ kh,
    u16* __restrict__ kl, int n4) {
  int stride = gridDim.x * blockDim.x;
  for (int i = blockIdx.x * blockDim.x + threadIdx.x; i < n4; i += stride) {
    u16x4 h, l;
    float4 x = ((const float4*)q)[i];
    split4(x, h, l);
    ((u16x4*)qh)[i] = h;
    ((u16x4*)ql)[i] = l;
    x = ((const float4*)k)[i];
    split4(x, h, l);
    ((u16x4*)kh)[i] = h;
    ((u16x4*)kl)[i] = l;
  }
}

// Weight prep: wqt = split(Wq^T); wot = bf16(Wo^T); wq_b = bf16(Wq) row-major.
__global__ void prep_w_t(const float* __restrict__ Wq,
                         const float* __restrict__ Wo, u16* __restrict__ wqt_h,
                         u16* __restrict__ wqt_l, u16* __restrict__ wot,
                         u16* __restrict__ wq_b, int D) {
  __shared__ float tq[32][33];
  __shared__ float to[32][33];
  int c0 = blockIdx.x * 32, r0 = blockIdx.y * 32;
  int tx = threadIdx.x, ty = threadIdx.y;
#pragma unroll
  for (int i = ty; i < 32; i += 8) {
    float xq = Wq[(size_t)(r0 + i) * D + c0 + tx];
    tq[i][tx] = xq;
    wq_b[(size_t)(r0 + i) * D + c0 + tx] = f2bf(xq);
    to[i][tx] = Wo[(size_t)(r0 + i) * D + c0 + tx];
  }
  __syncthreads();
#pragma unroll
  for (int i = ty; i < 32; i += 8) {
    float x = tq[tx][i];  // = Wq[(r0+tx)][c0+i]
    u16 h = f2bf(x);
    size_t o = (size_t)(c0 + i) * D + r0 + tx;
    wqt_h[o] = h;
    wqt_l[o] = f2bf(x - bf2f(h));
    wot[o] = f2bf(to[tx][i]);
  }
}

// Batched transpose f32 -> bf16: out[z][c][r] = bf16(in[z][r][c])
__global__ void transpose_f32_bf16(const float* __restrict__ in,
                                   u16* __restrict__ out, int R, int C) {
  __shared__ float tile[32][33];
  size_t zi = (size_t)blockIdx.z * R * C;
  int c0 = blockIdx.x * 32, r0 = blockIdx.y * 32;
  int tx = threadIdx.x, ty = threadIdx.y;
#pragma unroll
  for (int i = ty; i < 32; i += 8)
    tile[i][tx] = in[zi + (size_t)(r0 + i) * C + (c0 + tx)];
  __syncthreads();
#pragma unroll
  for (int i = ty; i < 32; i += 8)
    out[zi + (size_t)(c0 + i) * R + (r0 + tx)] = f2bf(tile[tx][i]);
}

// bqo[f] = sum_e bq[e]*Wo[e][f] + bo[f]   via wot (Wo^T bf16, row-contiguous).
__global__ __launch_bounds__(256) void bqo_kernel(const float* __restrict__ bq,
                                                  const u16* __restrict__ wot,
                                                  const float* __restrict__ bo,
                                                  float* __restrict__ bqo,
                                                  int D) {
  const int f = blockIdx.x * 4 + (threadIdx.x >> 6);
  const int lane = threadIdx.x & 63;
  const u16* wr_ = wot + (size_t)f * D;
  float s = 0.f;
  for (int e = lane; e < D; e += 64) s += bq[e] * bf2f(wr_[e]);
#pragma unroll
  for (int off = 32; off; off >>= 1) s += __shfl_xor(s, off);
  if (lane == 0) bqo[f] = s + bo[f];
}

// ---------------------------------------------------------------------------
// 128x128 2-barrier GEMM (kept only for the tiny Wqo GEMM).
// C[m][n] = sum_k A[m][k]*Bt[n][k] (+bias); EPI: 0=f32, 1=bf16.
// ---------------------------------------------------------------------------
template <int EPI>
__global__ __launch_bounds__(256, 2) void gemm_bt(
    const u16* __restrict__ Ah, const u16* __restrict__ Bh,
    const float* __restrict__ bias, float* __restrict__ Cf,
    u16* __restrict__ Ch, int M, int N, int K,
    long long sA, long long sB, long long sC) {
  __shared__ alignas(16) u16 As[128 * 32];
  __shared__ alignas(16) u16 Bs[128 * 32];

  const int t = threadIdx.x;
  const int lane = t & 63;
  const int w = t >> 6;
  const int wr = w >> 1, wc = w & 1;

  const long long zb = blockIdx.z;
  const u16* pA = Ah + zb * sA;
  const u16* pB = Bh + zb * sB;

  const int m0 = blockIdx.x * 128;
  const int n0 = blockIdx.y * 128;

  f32x4 acc[4][4] = {};

  const int row0 = t >> 2;
  const int colS = (t & 3) * 8;
  const int lds0 = (t & ~63) * 8;
  const int lds1 = (256 + (t & ~63)) * 8;

  const size_t aoff0 = (size_t)(m0 + row0) * K + colS;
  const size_t aoff1 = (size_t)(m0 + row0 + 64) * K + colS;
  const size_t boff0 = (size_t)(n0 + row0) * K + colS;
  const size_t boff1 = (size_t)(n0 + row0 + 64) * K + colS;

  for (int k0 = 0; k0 < K; k0 += 32) {
    __syncthreads();
    __builtin_amdgcn_global_load_lds(AS1(pA + aoff0 + k0), AS3(&As[lds0]), 16, 0, 0);
    __builtin_amdgcn_global_load_lds(AS1(pA + aoff1 + k0), AS3(&As[lds1]), 16, 0, 0);
    __builtin_amdgcn_global_load_lds(AS1(pB + boff0 + k0), AS3(&Bs[lds0]), 16, 0, 0);
    __builtin_amdgcn_global_load_lds(AS1(pB + boff1 + k0), AS3(&Bs[lds1]), 16, 0, 0);
    __syncthreads();

    const int fr = lane & 15;
    const int kc = (lane >> 4) * 8;
    bf16x8 a[4], b[4];
#pragma unroll
    for (int i = 0; i < 4; ++i)
      a[i] = *(const bf16x8*)&As[(wr * 64 + i * 16 + fr) * 32 + kc];
#pragma unroll
    for (int j = 0; j < 4; ++j)
      b[j] = *(const bf16x8*)&Bs[(wc * 64 + j * 16 + fr) * 32 + kc];
#pragma unroll
    for (int i = 0; i < 4; ++i)
#pragma unroll
      for (int j = 0; j < 4; ++j)
        acc[i][j] = __builtin_amdgcn_mfma_f32_16x16x32_bf16(a[i], b[j], acc[i][j], 0, 0, 0);
  }

  const int er = (lane >> 4) * 4;
  const int ec = lane & 15;
#pragma unroll
  for (int j = 0; j < 4; ++j) {
    const int gcol = n0 + wc * 64 + j * 16 + ec;
    const float bv = bias ? bias[gcol] : 0.0f;
#pragma unroll
    for (int i = 0; i < 4; ++i) {
      const int grow0 = m0 + wr * 64 + i * 16 + er;
#pragma unroll
      for (int r = 0; r < 4; ++r) {
        const float x = acc[i][j][r] + bv;
        const size_t off = (size_t)zb * sC + (size_t)(grow0 + r) * N + gcol;
        if constexpr (EPI == 0) Cf[off] = x;
        else Ch[off] = f2bf(x);
      }
    }
  }
}

// ---------------------------------------------------------------------------
// 256x256 8-phase split GEMM (Markidis 3-term) — unchanged from round 5.
// ---------------------------------------------------------------------------
#define A_LDS(BUF, H) ((BUF) * 32768 + (H) * 8192)
#define B_LDS(BUF, H) ((BUF) * 32768 + 16384 + (H) * 8192)

#define STAGE(DSTBASE, SH, SL, ROWBASE, KREAL)                                 \
  do {                                                                         \
    const u16* s0_ = (sc < 4 ? (SH) : (SL)) +                                  \
                     (size_t)((ROWBASE) + sr) * K + (KREAL) + ((sc & 3) << 3); \
    const u16* s1_ = s0_ + (size_t)64 * K;                                     \
    __builtin_amdgcn_global_load_lds(AS1(s0_), AS3(&lds[(DSTBASE) + ldsW]), 16, 0, 0); \
    __builtin_amdgcn_global_load_lds(AS1(s1_), AS3(&lds[(DSTBASE) + 4096 + ldsW]), 16, 0, 0); \
  } while (0)

#define LOADA(BUF, QM)                                                         \
  do {                                                                         \
    const int base_ = A_LDS(BUF, QM);                                          \
    _Pragma("unroll") for (int i_ = 0; i_ < 4; ++i_) {                         \
      const int r_ = wr * 64 + i_ * 16 + fr;                                   \
      const int sw_ = r_ & 7;                                                  \
      aH[i_] = *(const bf16x8*)&lds[base_ + r_ * 64 + ((ksl ^ sw_) << 3)];     \
      aL[i_] = *(const bf16x8*)&lds[base_ + r_ * 64 + (((4 + ksl) ^ sw_) << 3)]; \
    }                                                                          \
  } while (0)

#define LOADB(BUF, QN, BH, BL)                                                 \
  do {                                                                         \
    const int base_ = B_LDS(BUF, QN);                                          \
    _Pragma("unroll") for (int j_ = 0; j_ < 2; ++j_) {                         \
      const int r_ = wc * 32 + j_ * 16 + fr;                                   \
      const int sw_ = r_ & 7;                                                  \
      BH[j_] = *(const bf16x8*)&lds[base_ + r_ * 64 + ((ksl ^ sw_) << 3)];     \
      BL[j_] = *(const bf16x8*)&lds[base_ + r_ * 64 + (((4 + ksl) ^ sw_) << 3)]; \
    }                                                                          \
  } while (0)

#define MMAQ(QM, QN, BH, BL)                                                   \
  do {                                                                         \
    _Pragma("unroll") for (int i_ = 0; i_ < 4; ++i_) {                         \
      _Pragma("unroll") for (int j_ = 0; j_ < 2; ++j_) {                       \
        f32x4 c_ = acc[(QM) * 4 + i_][(QN) * 2 + j_];                          \
        c_ = __builtin_amdgcn_mfma_f32_16x16x32_bf16(aH[i_], BH[j_], c_, 0, 0, 0); \
        c_ = __builtin_amdgcn_mfma_f32_16x16x32_bf16(aH[i_], BL[j_], c_, 0, 0, 0); \
        c_ = __builtin_amdgcn_mfma_f32_16x16x32_bf16(aL[i_], BH[j_], c_, 0, 0, 0); \
        acc[(QM) * 4 + i_][(QN) * 2 + j_] = c_;                                \
      }                                                                        \
    }                                                                          \
  } while (0)

#define PH_PRE()                                                               \
  __builtin_amdgcn_s_barrier();                                                \
  asm volatile("s_waitcnt lgkmcnt(0)" ::: "memory");                           \
  __builtin_amdgcn_s_setprio(1)

#define PH_POST()                                                              \
  __builtin_amdgcn_s_setprio(0);                                               \
  __builtin_amdgcn_s_barrier()

template <int EPI>
__global__ __launch_bounds__(512, 2) void gemm8s(
    const u16* __restrict__ Ah, const u16* __restrict__ Al,
    const u16* __restrict__ Bh, const u16* __restrict__ Bl,
    const float* __restrict__ bias, float* __restrict__ Cf,
    u16* __restrict__ Ch, u16* __restrict__ Cl, int M, int N, int K,
    long long sA, long long sB, long long sC) {
  extern __shared__ u16 lds[];

  const int tt = threadIdx.x;
  const int lane = tt & 63;
  const int wv = tt >> 6;
  const int wr = wv >> 2;  // 0..1
  const int wc = wv & 3;   // 0..3
  const int fr = lane & 15;
  const int ksl = lane >> 4;  // 0..3

  const long long zb = blockIdx.z;
  const u16* pAh = Ah + zb * sA;
  const u16* pAl = Al + zb * sA;
  const u16* pBh = Bh + zb * sB;
  const u16* pBl = Bl + zb * sB;
  const int m0 = blockIdx.x * 256;
  const int n0 = blockIdx.y * 256;

  const int sr = tt >> 3;
  const int ss = tt & 7;
  const int sc = ss ^ (sr & 7);
  const int ldsW = (tt & ~63) * 8;

  f32x4 acc[8][4] = {};
  bf16x8 aH[4], aL[4], bH0[2], bL0[2], bH1[2], bL1[2];

  const int NT = K / 32;
  const int NITER = NT / 2;

  STAGE(A_LDS(0, 0), pAh, pAl, m0, 0);
  STAGE(B_LDS(0, 0), pBh, pBl, n0, 0);
  STAGE(A_LDS(0, 1), pAh, pAl, m0 + 128, 0);
  STAGE(B_LDS(0, 1), pBh, pBl, n0 + 128, 0);
  STAGE(A_LDS(1, 0), pAh, pAl, m0, 32);
  STAGE(B_LDS(1, 0), pBh, pBl, n0, 32);
  asm volatile("s_waitcnt vmcnt(4)" ::: "memory");
  __builtin_amdgcn_s_barrier();
  __builtin_amdgcn_sched_barrier(0);

  for (int it = 0; it < NITER; ++it) {
    const int t0 = 2 * it;
    const int k1 = (t0 + 1) * 32;
    const int k2 = (t0 + 2 < NT ? t0 + 2 : NT - 1) * 32;
    const int k3 = (t0 + 3 < NT ? t0 + 3 : NT - 1) * 32;

    LOADA(0, 0);
    LOADB(0, 0, bH0, bL0);
    STAGE(A_LDS(1, 1), pAh, pAl, m0 + 128, k1);
    PH_PRE();
    MMAQ(0, 0, bH0, bL0);
    PH_POST();

    LOADB(0, 1, bH1, bL1);
    STAGE(B_LDS(1, 1), pBh, pBl, n0 + 128, k1);
    PH_PRE();
    MMAQ(0, 1, bH1, bL1);
    PH_POST();

    LOADA(0, 1);
    STAGE(A_LDS(0, 0), pAh, pAl, m0, k2);
    PH_PRE();
    MMAQ(1, 0, bH0, bL0);
    PH_POST();

    STAGE(B_LDS(0, 0), pBh, pBl, n0, k2);
    __builtin_amdgcn_s_barrier();
    asm volatile("s_waitcnt lgkmcnt(0)" ::: "memory");
    __builtin_amdgcn_s_setprio(1);
    MMAQ(1, 1, bH1, bL1);
    __builtin_amdgcn_s_setprio(0);
    asm volatile("s_waitcnt vmcnt(4)" ::: "memory");
    __builtin_amdgcn_s_barrier();
    __builtin_amdgcn_sched_barrier(0);

    LOADA(1, 0);
    LOADB(1, 0, bH0, bL0);
    STAGE(A_LDS(0, 1), pAh, pAl, m0 + 128, k2);
    PH_PRE();
    MMAQ(0, 0, bH0, bL0);
    PH_POST();

    LOADB(1, 1, bH1, bL1);
    STAGE(B_LDS(0, 1), pBh, pBl, n0 + 128, k2);
    PH_PRE();
    MMAQ(0, 1, bH1, bL1);
    PH_POST();

    LOADA(1, 1);
    STAGE(B_LDS(1, 0), pBh, pBl, n0, k3);
    PH_PRE();
    MMAQ(1, 0, bH0, bL0);
    PH_POST();

    STAGE(A_LDS(1, 0), pAh, pAl, m0, k3);
    __builtin_amdgcn_s_barrier();
    asm volatile("s_waitcnt lgkmcnt(0)" ::: "memory");
    __builtin_amdgcn_s_setprio(1);
    MMAQ(1, 1, bH1, bL1);
    __builtin_amdgcn_s_setprio(0);
    asm volatile("s_waitcnt vmcnt(4)" ::: "memory");
    __builtin_amdgcn_s_barrier();
    __builtin_amdgcn_sched_barrier(0);
  }

  const int er = (lane >> 4) * 4;
  const int ec = lane & 15;
#pragma unroll
  for (int fi = 0; fi < 8; ++fi) {
    const int qm = fi >> 2, i = fi & 3;
    const int grow0 = m0 + qm * 128 + wr * 64 + i * 16 + er;
#pragma unroll
    for (int fj = 0; fj < 4; ++fj) {
      const int qn = fj >> 1, j = fj & 1;
      const int gcol = n0 + qn * 128 + wc * 32 + j * 16 + ec;
      const float bv = bias ? bias[gcol] : 0.0f;
#pragma unroll
      for (int r = 0; r < 4; ++r) {
        const float x = acc[fi][fj][r] + bv;
        const size_t off = (size_t)zb * sC + (size_t)(grow0 + r) * N + gcol;
        if constexpr (EPI == 0) {
          Cf[off] = x;
        } else {
          const u16 h = f2bf(x);
          Ch[off] = h;
          Cl[off] = f2bf(x - bf2f(h));
        }
      }
    }
  }
}

// ---------------------------------------------------------------------------
// gemm8p: plain-bf16 256x128-tile, BK=64, 4-phase counted-vmcnt pipeline.
// Same conflict-free LDS addressing as gemm8s. 512 thr (8 waves 2Mx4N),
// per-wave out 128x32. LDS: A(buf,h)=buf*24576+h*8192 (128 rows x 64K each),
// B(buf)=buf*24576+16384 (128 rows x 64K). 96 KiB total, 1 block/CU.
// Stage schedule: P1:B' P2:A'h0 P3:A'h1; vmcnt(2) at end of P1 and P4 only.
// EPI: 0 = f32 out (+bias), 1 = bf16 out.
// ---------------------------------------------------------------------------
#define STG_P(DSTBASE, SRC, ROWBASE, KREAL)                                    \
  do {                                                                         \
    const u16* s0_ = (SRC) + (size_t)((ROWBASE) + sr) * K + (KREAL) + (sc << 3); \
    const u16* s1_ = s0_ + (size_t)64 * K;                                     \
    __builtin_amdgcn_global_load_lds(AS1(s0_), AS3(&lds[(DSTBASE) + ldsW]), 16, 0, 0); \
    __builtin_amdgcn_global_load_lds(AS1(s1_), AS3(&lds[(DSTBASE) + 4096 + ldsW]), 16, 0, 0); \
  } while (0)

#define LDA_P(BUF, QM, S)                                                      \
  do {                                                                         \
    const int base_ = (BUF) * 24576 + (QM) * 8192;                             \
    _Pragma("unroll") for (int i_ = 0; i_ < 4; ++i_) {                         \
      const int r_ = wr * 64 + i_ * 16 + fr;                                   \
      a[i_] = *(const bf16x8*)&lds[base_ + r_ * 64 + (((((S) * 4 + ksl)) ^ (r_ & 7)) << 3)]; \
    }                                                                          \
  } while (0)

#define LDB_P(BUF, S)                                                          \
  do {                                                                         \
    const int base_ = (BUF) * 24576 + 16384;                                   \
    _Pragma("unroll") for (int j_ = 0; j_ < 2; ++j_) {                         \
      const int r_ = wc * 32 + j_ * 16 + fr;                                   \
      b[j_] = *(const bf16x8*)&lds[base_ + r_ * 64 + (((((S) * 4 + ksl)) ^ (r_ & 7)) << 3)]; \
    }                                                                          \
  } while (0)

#define MMA_P(QM)                                                              \
  do {                                                                         \
    _Pragma("unroll") for (int i_ = 0; i_ < 4; ++i_) {                         \
      _Pragma("unroll") for (int j_ = 0; j_ < 2; ++j_) {                       \
        acc[(QM) * 4 + i_][j_] = __builtin_amdgcn_mfma_f32_16x16x32_bf16(      \
            a[i_], b[j_], acc[(QM) * 4 + i_][j_], 0, 0, 0);                    \
      }                                                                        \
    }                                                                          \
  } while (0)

template <int EPI>
__global__ __launch_bounds__(512, 2) void gemm8p(
    const u16* __restrict__ A, const u16* __restrict__ B,
    const float* __restrict__ bias, float* __restrict__ Cf,
    u16* __restrict__ Ch, int M, int N, int K,
    long long sA, long long sB, long long sC) {
  extern __shared__ u16 lds[];

  const int tt = threadIdx.x;
  const int lane = tt & 63;
  const int wv = tt >> 6;
  const int wr = wv >> 2;  // 0..1
  const int wc = wv & 3;   // 0..3
  const int fr = lane & 15;
  const int ksl = lane >> 4;

  const long long zb = blockIdx.z;
  const u16* pA = A + zb * sA;
  const u16* pB = B + zb * sB;
  const int m0 = blockIdx.x * 256;
  const int n0 = blockIdx.y * 128;

  const int sr = tt >> 3;
  const int ss = tt & 7;
  const int sc = ss ^ (sr & 7);
  const int ldsW = (tt & ~63) * 8;

  f32x4 acc[8][2] = {};
  bf16x8 a[4], b[2];

  const int NT = K / 64;

  // prologue: tile0 (B, A h0, A h1); wait B+Ah0 (leave Ah1 in flight)
  STG_P(16384, pB, n0, 0);
  STG_P(0, pA, m0, 0);
  STG_P(8192, pA, m0 + 128, 0);
  asm volatile("s_waitcnt vmcnt(2)" ::: "memory");
  __builtin_amdgcn_s_barrier();
  __builtin_amdgcn_sched_barrier(0);

  for (int it = 0; it < NT; ++it) {
    const int cur = it & 1;
    const int nb = (cur ^ 1) * 24576;
    const int kn = (it + 1 < NT ? it + 1 : NT - 1) * 64;

    // P1: read A(h0,s0)+B(s0) | stage B' | vmcnt(2) after MFMA
    LDA_P(cur, 0, 0);
    LDB_P(cur, 0);
    STG_P(nb + 16384, pB, n0, kn);
    PH_PRE();
    MMA_P(0);
    __builtin_amdgcn_s_setprio(0);
    asm volatile("s_waitcnt vmcnt(2)" ::: "memory");
    __builtin_amdgcn_s_barrier();
    __builtin_amdgcn_sched_barrier(0);

    // P2: read A(h1,s0) | stage A'h0
    LDA_P(cur, 1, 0);
    STG_P(nb + 0, pA, m0, kn);
    PH_PRE();
    MMA_P(1);
    PH_POST();

    // P3: read A(h0,s1)+B(s1) | stage A'h1
    LDA_P(cur, 0, 1);
    LDB_P(cur, 1);
    STG_P(nb + 8192, pA, m0 + 128, kn);
    PH_PRE();
    MMA_P(0);
    PH_POST();

    // P4: read A(h1,s1) | vmcnt(2) after MFMA
    LDA_P(cur, 1, 1);
    PH_PRE();
    MMA_P(1);
    __builtin_amdgcn_s_setprio(0);
    asm volatile("s_waitcnt vmcnt(2)" ::: "memory");
    __builtin_amdgcn_s_barrier();
    __builtin_amdgcn_sched_barrier(0);
  }

  // epilogue: C/D map col=lane&15, row=(lane>>4)*4+reg
  const int er = (lane >> 4) * 4;
  const int ec = lane & 15;
#pragma unroll
  for (int fi = 0; fi < 8; ++fi) {
    const int qm = fi >> 2, i = fi & 3;
    const int grow0 = m0 + qm * 128 + wr * 64 + i * 16 + er;
#pragma unroll
    for (int j = 0; j < 2; ++j) {
      const int gcol = n0 + wc * 32 + j * 16 + ec;
      const float bv = bias ? bias[gcol] : 0.0f;
#pragma unroll
      for (int r = 0; r < 4; ++r) {
        const float x = acc[fi][j][r] + bv;
        const size_t off = (size_t)zb * sC + (size_t)(grow0 + r) * N + gcol;
        if constexpr (EPI == 0) Cf[off] = x;
        else Ch[off] = f2bf(x);
      }
    }
  }
}

// ---------------------------------------------------------------------------
// Row softmax: in-place fp32 (weights output) + bf16 copy (P for PV GEMM).
// ---------------------------------------------------------------------------
__global__ __launch_bounds__(256) void softmax_rows(float* __restrict__ S,
                                                    u16* __restrict__ P) {
  const int T = 2048;
  const size_t row = blockIdx.x;
  float* sr = S + row * T;
  u16* pr = P + row * T;
  const int t = threadIdx.x;
  const int w = t >> 6, lane = t & 63;
  __shared__ float red[8];

  float v[8];
  float mx = -1e30f;
#pragma unroll
  for (int i = 0; i < 8; ++i) {
    v[i] = sr[t + 256 * i];
    mx = fmaxf(mx, v[i]);
  }
#pragma unroll
  for (int off = 32; off; off >>= 1) mx = fmaxf(mx, __shfl_xor(mx, off));
  if (lane == 0) red[w] = mx;
  __syncthreads();
  mx = fmaxf(fmaxf(red[0], red[1]), fmaxf(red[2], red[3]));

  float s = 0.f;
#pragma unroll
  for (int i = 0; i < 8; ++i) {
    v[i] = __expf(v[i] - mx);
    s += v[i];
  }
#pragma unroll
  for (int off = 32; off; off >>= 1) s += __shfl_xor(s, off);
  if (lane == 0) red[4 + w] = s;
  __syncthreads();
  s = (red[4] + red[5]) + (red[6] + red[7]);
  const float inv = 1.0f / s;
#pragma unroll
  for (int i = 0; i < 8; ++i) {
    const float wv = v[i] * inv;
    sr[t + 256 * i] = wv;
    pr[t + 256 * i] = f2bf(wv);
  }
}

// ---------------------------------------------------------------------------
extern "C" void kernel_launch(void* const* d_in, const int* in_sizes, int n_in,
                              void* d_out, int out_size, void* d_ws,
                              size_t ws_size, hipStream_t stream) {
  (void)in_sizes; (void)n_in; (void)out_size; (void)ws_size;
  const float* query = (const float*)d_in[0];
  const float* key   = (const float*)d_in[1];
  const float* value = (const float*)d_in[2];
  const float* Wq    = (const float*)d_in[3];
  const float* bq    = (const float*)d_in[4];
  const float* Wo    = (const float*)d_in[5];
  const float* bo    = (const float*)d_in[6];

  const int S = 2048, D = 1024;
  const size_t n = (size_t)4 * S * D;  // 8,388,608

  float* out = (float*)d_out;          // (B,S,D) f32, 32MB
  float* wts = out + n;                // (B,S,T) f32, 64MB

  char* ws = (char*)d_ws;
  u16* wqt_h = (u16*)(ws);                   // 2MB  Wq^T hi
  u16* wqt_l = (u16*)(ws + (2ull << 20));    // 2MB  Wq^T lo
  u16* wot   = (u16*)(ws + (4ull << 20));    // 2MB  Wo^T bf16
  u16* wq_b  = (u16*)(ws + (6ull << 20));    // 2MB  Wq bf16 row-major
  u16* wqoT  = (u16*)(ws + (8ull << 20));    // 2MB  (Wq@Wo)^T bf16
  float* bqo = (float*)(ws + (10ull << 20)); // 4KB
  u16* QKh   = (u16*)(ws + (12ull << 20));   // 32MB: Q rows then K rows
  u16* QKl   = (u16*)(ws + (44ull << 20));   // 32MB  (total ws: 76MB)
  u16* P   = QKh;  // 32MB (QKh dead after score GEMM)
  u16* tmp = QKl;  // 16MB (QKl dead after score GEMM); tmp = P@value^T

  u16* qkin_h = (u16*)wts;  // scratch in d_out (dead before score write)
  u16* qkin_l = qkin_h + 2 * n;
  u16* valT = (u16*)out;    // (B, D, T) bf16, 16MB (dead before out write)

  hipFuncSetAttribute((const void*)&gemm8s<2>,
                      hipFuncAttributeMaxDynamicSharedMemorySize, 131072);
  hipFuncSetAttribute((const void*)&gemm8s<0>,
                      hipFuncAttributeMaxDynamicSharedMemorySize, 131072);
  hipFuncSetAttribute((const void*)&gemm8p<1>,
                      hipFuncAttributeMaxDynamicSharedMemorySize, 98304);
  hipFuncSetAttribute((const void*)&gemm8p<0>,
                      hipFuncAttributeMaxDynamicSharedMemorySize, 98304);

  // 1. split q,k inputs (stacked)
  split_qk<<<2048, 256, 0, stream>>>(query, key, qkin_h, qkin_l, qkin_h + n,
                                     qkin_l + n, (int)(n / 4));
  // 2. weight prep
  prep_w_t<<<dim3(D / 32, D / 32), dim3(32, 8), 0, stream>>>(
      Wq, Wo, wqt_h, wqt_l, wot, wq_b, D);
  // 3. value^T (f32 -> bf16), per batch
  transpose_f32_bf16<<<dim3(D / 32, S / 32, 4), dim3(32, 8), 0, stream>>>(
      value, valT, S, D);
  // 4. WqoT[f][e] = sum_d Wo^T[f][d] * Wq[e][d]   (= (Wq@Wo)^T)
  gemm_bt<1><<<dim3(8, 8, 1), 256, 0, stream>>>(
      wot, wq_b, nullptr, nullptr, wqoT, 1024, 1024, 1024, 0, 0, 0);
  // 5. bqo = bq@Wo + bo
  bqo_kernel<<<256, 256, 0, stream>>>(bq, wot, bo, bqo, D);
  // 6. [Q;K] = [q;k] @ Wq + bq  (split in, split out) — 8-phase 256^2
  gemm8s<2><<<dim3(64, 4, 1), 512, 131072, stream>>>(
      qkin_h, qkin_l, wqt_h, wqt_l, bq, nullptr, QKh, QKl, 16384, 1024, 1024,
      0, 0, 0);
  // 7. score = Q @ K^T (split, fp32 out) — 8-phase 256^2
  gemm8s<0><<<dim3(8, 8, 4), 512, 131072, stream>>>(
      QKh, QKl, QKh + n, QKl + n, nullptr, wts, nullptr, nullptr, 2048, 2048,
      1024, (long long)S * D, (long long)S * D, (long long)S * S);
  // 8. softmax rows (in-place) + bf16 P
  softmax_rows<<<8192, 256, 0, stream>>>(wts, P);
  // 9. tmp = P @ value^T — gemm8p 256x128, grid 256 blocks
  gemm8p<1><<<dim3(8, 8, 4), 512, 98304, stream>>>(
      P, valT, nullptr, nullptr, tmp, 2048, 1024, 2048, (long long)S * S,
      (long long)D * S, (long long)S * D);
  // 10. out = tmp @ Wqo + bqo — gemm8p 256x128 on flattened M=8192
  gemm8p<0><<<dim3(32, 8, 1), 512, 98304, stream>>>(
      tmp, wqoT, bqo, out, nullptr, 8192, 1024, 1024, 0, 0, 0);
}

// Round 7
// 273.676 us; speedup vs baseline: 2.2069x; 1.2244x over previous
//
#include <hip/hip_runtime.h>

typedef unsigned short u16;
typedef unsigned int u32;
typedef signed char i8;
typedef __bf16 bf16x8 __attribute__((ext_vector_type(8)));
typedef float f32x4 __attribute__((ext_vector_type(4)));
typedef int i32x4 __attribute__((ext_vector_type(4)));
typedef i8 i8x4 __attribute__((ext_vector_type(4)));

#define AS1(p) ((const __attribute__((address_space(1))) void*)(p))
#define AS3(p) ((__attribute__((address_space(3))) void*)(p))

__device__ __forceinline__ u16 f2bf(float x) {
  u32 u = __float_as_uint(x);
  u32 r = u + 0x7fffu + ((u >> 16) & 1u);
  return (u16)(r >> 16);
}
__device__ __forceinline__ float bf2f(u16 h) {
  return __uint_as_float(((u32)h) << 16);
}

// ---------------------------------------------------------------------------
// i8 dual-split quantizer: x ~= s*(h + l/256), |err| <= s/512.
// ---------------------------------------------------------------------------
#define S_IN (8.0f / 127.0f)
#define S_W (0.25f / 127.0f)
#define S_QK (8.0f / 127.0f)
#define INV_S_IN (127.0f / 8.0f)
#define INV_S_W (508.0f)
#define INV_S_QK (127.0f / 8.0f)

__device__ __forceinline__ int2 q8i(float x, float inv_s) {
  float t = fminf(fmaxf(x * inv_s, -126.99f), 126.99f);
  float hf = rintf(t);
  float lf = fminf(fmaxf(rintf((t - hf) * 256.0f), -127.0f), 127.0f);
  return make_int2((int)hf, (int)lf);
}

// split q,k (f32) -> i8 h/l pairs
__global__ __launch_bounds__(256) void split_qk_i8(
    const float* __restrict__ q, const float* __restrict__ k,
    i8* __restrict__ qh, i8* __restrict__ ql, i8* __restrict__ kh,
    i8* __restrict__ kl, int n4) {
  int stride = gridDim.x * blockDim.x;
  for (int i = blockIdx.x * blockDim.x + threadIdx.x; i < n4; i += stride) {
    float4 x = ((const float4*)q)[i];
    float xs[4] = {x.x, x.y, x.z, x.w};
    i8x4 h, l;
#pragma unroll
    for (int e = 0; e < 4; ++e) {
      int2 r = q8i(xs[e], INV_S_IN);
      h[e] = (i8)r.x;
      l[e] = (i8)r.y;
    }
    ((i8x4*)qh)[i] = h;
    ((i8x4*)ql)[i] = l;
    x = ((const float4*)k)[i];
    float ys[4] = {x.x, x.y, x.z, x.w};
#pragma unroll
    for (int e = 0; e < 4; ++e) {
      int2 r = q8i(ys[e], INV_S_IN);
      h[e] = (i8)r.x;
      l[e] = (i8)r.y;
    }
    ((i8x4*)kh)[i] = h;
    ((i8x4*)kl)[i] = l;
  }
}

// Weight prep: wqt = i8-split(Wq^T); wot = bf16(Wo^T); wq_b = bf16(Wq).
__global__ void prep_w_i8(const float* __restrict__ Wq,
                          const float* __restrict__ Wo, i8* __restrict__ wqt_h,
                          i8* __restrict__ wqt_l, u16* __restrict__ wot,
                          u16* __restrict__ wq_b, int D) {
  __shared__ float tq[32][33];
  __shared__ float to[32][33];
  int c0 = blockIdx.x * 32, r0 = blockIdx.y * 32;
  int tx = threadIdx.x, ty = threadIdx.y;
#pragma unroll
  for (int i = ty; i < 32; i += 8) {
    float xq = Wq[(size_t)(r0 + i) * D + c0 + tx];
    tq[i][tx] = xq;
    wq_b[(size_t)(r0 + i) * D + c0 + tx] = f2bf(xq);
    to[i][tx] = Wo[(size_t)(r0 + i) * D + c0 + tx];
  }
  __syncthreads();
#pragma unroll
  for (int i = ty; i < 32; i += 8) {
    float x = tq[tx][i];  // = Wq[(r0+tx)][c0+i]
    int2 r = q8i(x, INV_S_W);
    size_t o = (size_t)(c0 + i) * D + r0 + tx;
    wqt_h[o] = (i8)r.x;
    wqt_l[o] = (i8)r.y;
    wot[o] = f2bf(to[tx][i]);
  }
}

// Batched transpose f32 -> bf16: out[z][c][r] = bf16(in[z][r][c])
__global__ void transpose_f32_bf16(const float* __restrict__ in,
                                   u16* __restrict__ out, int R, int C) {
  __shared__ float tile[32][33];
  size_t zi = (size_t)blockIdx.z * R * C;
  int c0 = blockIdx.x * 32, r0 = blockIdx.y * 32;
  int tx = threadIdx.x, ty = threadIdx.y;
#pragma unroll
  for (int i = ty; i < 32; i += 8)
    tile[i][tx] = in[zi + (size_t)(r0 + i) * C + (c0 + tx)];
  __syncthreads();
#pragma unroll
  for (int i = ty; i < 32; i += 8)
    out[zi + (size_t)(c0 + i) * R + (r0 + tx)] = f2bf(tile[tx][i]);
}

// bqo[f] = sum_e bq[e]*Wo[e][f] + bo[f]   via wot (Wo^T bf16).
__global__ __launch_bounds__(256) void bqo_kernel(const float* __restrict__ bq,
                                                  const u16* __restrict__ wot,
                                                  const float* __restrict__ bo,
                                                  float* __restrict__ bqo,
                                                  int D) {
  const int f = blockIdx.x * 4 + (threadIdx.x >> 6);
  const int lane = threadIdx.x & 63;
  const u16* wr_ = wot + (size_t)f * D;
  float s = 0.f;
  for (int e = lane; e < D; e += 64) s += bq[e] * bf2f(wr_[e]);
#pragma unroll
  for (int off = 32; off; off >>= 1) s += __shfl_xor(s, off);
  if (lane == 0) bqo[f] = s + bo[f];
}

// ---------------------------------------------------------------------------
// 128x128 2-barrier GEMM (only for the tiny Wqo GEMM).
// ---------------------------------------------------------------------------
template <int EPI>
__global__ __launch_bounds__(256, 2) void gemm_bt(
    const u16* __restrict__ Ah, const u16* __restrict__ Bh,
    const float* __restrict__ bias, float* __restrict__ Cf,
    u16* __restrict__ Ch, int M, int N, int K,
    long long sA, long long sB, long long sC) {
  __shared__ alignas(16) u16 As[128 * 32];
  __shared__ alignas(16) u16 Bs[128 * 32];

  const int t = threadIdx.x;
  const int lane = t & 63;
  const int w = t >> 6;
  const int wr = w >> 1, wc = w & 1;

  const long long zb = blockIdx.z;
  const u16* pA = Ah + zb * sA;
  const u16* pB = Bh + zb * sB;

  const int m0 = blockIdx.x * 128;
  const int n0 = blockIdx.y * 128;

  f32x4 acc[4][4] = {};

  const int row0 = t >> 2;
  const int colS = (t & 3) * 8;
  const int lds0 = (t & ~63) * 8;
  const int lds1 = (256 + (t & ~63)) * 8;

  const size_t aoff0 = (size_t)(m0 + row0) * K + colS;
  const size_t aoff1 = (size_t)(m0 + row0 + 64) * K + colS;
  const size_t boff0 = (size_t)(n0 + row0) * K + colS;
  const size_t boff1 = (size_t)(n0 + row0 + 64) * K + colS;

  for (int k0 = 0; k0 < K; k0 += 32) {
    __syncthreads();
    __builtin_amdgcn_global_load_lds(AS1(pA + aoff0 + k0), AS3(&As[lds0]), 16, 0, 0);
    __builtin_amdgcn_global_load_lds(AS1(pA + aoff1 + k0), AS3(&As[lds1]), 16, 0, 0);
    __builtin_amdgcn_global_load_lds(AS1(pB + boff0 + k0), AS3(&Bs[lds0]), 16, 0, 0);
    __builtin_amdgcn_global_load_lds(AS1(pB + boff1 + k0), AS3(&Bs[lds1]), 16, 0, 0);
    __syncthreads();

    const int fr = lane & 15;
    const int kc = (lane >> 4) * 8;
    bf16x8 a[4], b[4];
#pragma unroll
    for (int i = 0; i < 4; ++i)
      a[i] = *(const bf16x8*)&As[(wr * 64 + i * 16 + fr) * 32 + kc];
#pragma unroll
    for (int j = 0; j < 4; ++j)
      b[j] = *(const bf16x8*)&Bs[(wc * 64 + j * 16 + fr) * 32 + kc];
#pragma unroll
    for (int i = 0; i < 4; ++i)
#pragma unroll
      for (int j = 0; j < 4; ++j)
        acc[i][j] = __builtin_amdgcn_mfma_f32_16x16x32_bf16(a[i], b[j], acc[i][j], 0, 0, 0);
  }

  const int er = (lane >> 4) * 4;
  const int ec = lane & 15;
#pragma unroll
  for (int j = 0; j < 4; ++j) {
    const int gcol = n0 + wc * 64 + j * 16 + ec;
    const float bv = bias ? bias[gcol] : 0.0f;
#pragma unroll
    for (int i = 0; i < 4; ++i) {
      const int grow0 = m0 + wr * 64 + i * 16 + er;
#pragma unroll
      for (int r = 0; r < 4; ++r) {
        const float x = acc[i][j][r] + bv;
        const size_t off = (size_t)zb * sC + (size_t)(grow0 + r) * N + gcol;
        if constexpr (EPI == 0) Cf[off] = x;
        else Ch[off] = f2bf(x);
      }
    }
  }
}

#define PH_PRE()                                                               \
  __builtin_amdgcn_s_barrier();                                                \
  asm volatile("s_waitcnt lgkmcnt(0)" ::: "memory");                           \
  __builtin_amdgcn_s_setprio(1)

#define PH_POST()                                                              \
  __builtin_amdgcn_s_setprio(0);                                               \
  __builtin_amdgcn_s_barrier()

// ---------------------------------------------------------------------------
// gemm8i: i8 dual-split GEMM, 256x128 tile, BK=64 real K, 16x16x64 i8 MFMA.
// C = sAB*(H + X/256) (+bias). Byte-identical LDS geometry to the proven
// gemm8s: 128 B/row (h chunks 0-3, l chunks 4-7 of 16 B), XOR-swizzled,
// 16-row fragment pattern (2-way LDS aliasing = free). 512 thr (8 waves 2x4),
// per-wave out 128x32; accH + accX = 128 VGPR. 96 KiB LDS double-buffered.
// 8 phases / 2 K-tiles; stages mirror gemm8s distances; vmcnt(2) at P4/P8.
// EPI: 0 = f32 out, 2 = i8 h/l split out (re-quantized with INV_S_QK).
// ---------------------------------------------------------------------------
#define STG_I(DSTBASE, SH, SL, ROWBASE, KREAL)                                 \
  do {                                                                         \
    const i8* s0_ = (sc < 4 ? (SH) : (SL)) +                                   \
                    (size_t)((ROWBASE) + sr) * K + (KREAL) + ((sc & 3) << 4);  \
    const i8* s1_ = s0_ + (size_t)64 * K;                                      \
    __builtin_amdgcn_global_load_lds(AS1(s0_), AS3(&lds8[(DSTBASE) + ldsB]), 16, 0, 0); \
    __builtin_amdgcn_global_load_lds(AS1(s1_), AS3(&lds8[(DSTBASE) + 8192 + ldsB]), 16, 0, 0); \
  } while (0)

#define LDA_I(BUF, QM)                                                         \
  do {                                                                         \
    const int base_ = (BUF) * 49152;                                           \
    _Pragma("unroll") for (int i_ = 0; i_ < 4; ++i_) {                         \
      const int r_ = (QM) * 128 + wr * 64 + i_ * 16 + fr;                      \
      ah_[i_] = *(const i32x4*)&lds8[base_ + r_ * 128 + ((ksl ^ (r_ & 7)) << 4)]; \
      al_[i_] = *(const i32x4*)&lds8[base_ + r_ * 128 + (((4 + ksl) ^ (r_ & 7)) << 4)]; \
    }                                                                          \
  } while (0)

#define LDB_I(BUF, J, BH, BL)                                                  \
  do {                                                                         \
    const int base_ = (BUF) * 49152 + 32768;                                   \
    const int r_ = wc * 32 + (J) * 16 + fr;                                    \
    BH = *(const i32x4*)&lds8[base_ + r_ * 128 + ((ksl ^ (r_ & 7)) << 4)];     \
    BL = *(const i32x4*)&lds8[base_ + r_ * 128 + (((4 + ksl) ^ (r_ & 7)) << 4)]; \
  } while (0)

#define MMA_I(QM, J, BH, BL)                                                   \
  do {                                                                         \
    _Pragma("unroll") for (int i_ = 0; i_ < 4; ++i_) {                         \
      accH[(QM) * 4 + i_][J] = __builtin_amdgcn_mfma_i32_16x16x64_i8(          \
          ah_[i_], BH, accH[(QM) * 4 + i_][J], 0, 0, 0);                       \
      accX[(QM) * 4 + i_][J] = __builtin_amdgcn_mfma_i32_16x16x64_i8(          \
          ah_[i_], BL, accX[(QM) * 4 + i_][J], 0, 0, 0);                       \
      accX[(QM) * 4 + i_][J] = __builtin_amdgcn_mfma_i32_16x16x64_i8(          \
          al_[i_], BH, accX[(QM) * 4 + i_][J], 0, 0, 0);                       \
    }                                                                          \
  } while (0)

template <int EPI>
__global__ __launch_bounds__(512, 2) void gemm8i(
    const i8* __restrict__ Ah, const i8* __restrict__ Al,
    const i8* __restrict__ Bh, const i8* __restrict__ Bl,
    const float* __restrict__ bias, float sAB, float* __restrict__ Cf,
    i8* __restrict__ Ch, i8* __restrict__ Cl, int M, int N, int K,
    long long sA, long long sB, long long sC) {
  extern __shared__ i8 lds8[];

  const int tt = threadIdx.x;
  const int lane = tt & 63;
  const int wv = tt >> 6;
  const int wr = wv >> 2;  // 0..1
  const int wc = wv & 3;   // 0..3
  const int fr = lane & 15;
  const int ksl = lane >> 4;  // 0..3

  const long long zb = blockIdx.z;
  const i8* pAh = Ah + zb * sA;
  const i8* pAl = Al + zb * sA;
  const i8* pBh = Bh + zb * sB;
  const i8* pBl = Bl + zb * sB;
  const int m0 = blockIdx.x * 256;
  const int n0 = blockIdx.y * 128;

  const int sr = tt >> 3;
  const int ss = tt & 7;
  const int sc = ss ^ (sr & 7);
  const int ldsB = (tt & ~63) * 16;

  i32x4 accH[8][2] = {};
  i32x4 accX[8][2] = {};
  i32x4 ah_[4], al_[4], b0h, b0l, b1h, b1l;

  const int NT = K / 64;
  const int NITER = NT / 2;

  // prologue: t0 full (A h0,h1 + B) + t1's A(h0)
  STG_I(0, pAh, pAl, m0, 0);              // A(0,h0)
  STG_I(16384, pAh, pAl, m0 + 128, 0);    // A(0,h1)
  STG_I(32768, pBh, pBl, n0, 0);          // B(0)
  STG_I(49152, pAh, pAl, m0, 64);         // A(1,h0) <- t1
  asm volatile("s_waitcnt vmcnt(2)" ::: "memory");
  __builtin_amdgcn_s_barrier();
  __builtin_amdgcn_sched_barrier(0);

  for (int it = 0; it < NITER; ++it) {
    const int t0 = 2 * it;
    const int k1 = (t0 + 1) * 64;
    const int k2 = (t0 + 2 < NT ? t0 + 2 : NT - 1) * 64;
    const int k3 = (t0 + 3 < NT ? t0 + 3 : NT - 1) * 64;

    // P1: (qm0,j0) buf0 | stage A(1,h1) <- t1
    LDA_I(0, 0);
    LDB_I(0, 0, b0h, b0l);
    STG_I(49152 + 16384, pAh, pAl, m0 + 128, k1);
    PH_PRE();
    MMA_I(0, 0, b0h, b0l);
    PH_POST();

    // P2: (qm0,j1) buf0 | stage B(1) <- t1
    LDB_I(0, 1, b1h, b1l);
    STG_I(49152 + 32768, pBh, pBl, n0, k1);
    PH_PRE();
    MMA_I(0, 1, b1h, b1l);
    PH_POST();

    // P3: (qm1,j0) buf0 | stage A(0,h0) <- t2
    LDA_I(0, 1);
    STG_I(0, pAh, pAl, m0, k2);
    PH_PRE();
    MMA_I(1, 0, b0h, b0l);
    PH_POST();

    // P4: (qm1,j1) buf0 | vmcnt(2) -> buf1 (t1) fully landed
    PH_PRE();
    MMA_I(1, 1, b1h, b1l);
    __builtin_amdgcn_s_setprio(0);
    asm volatile("s_waitcnt vmcnt(2)" ::: "memory");
    __builtin_amdgcn_s_barrier();
    __builtin_amdgcn_sched_barrier(0);

    // P5: (qm0,j0) buf1 | stage A(0,h1) <- t2
    LDA_I(1, 0);
    LDB_I(1, 0, b0h, b0l);
    STG_I(16384, pAh, pAl, m0 + 128, k2);
    PH_PRE();
    MMA_I(0, 0, b0h, b0l);
    PH_POST();

    // P6: (qm0,j1) buf1 | stage B(0) <- t2
    LDB_I(1, 1, b1h, b1l);
    STG_I(32768, pBh, pBl, n0, k2);
    PH_PRE();
    MMA_I(0, 1, b1h, b1l);
    PH_POST();

    // P7: (qm1,j0) buf1 | stage A(1,h0) <- t3
    LDA_I(1, 1);
    STG_I(49152, pAh, pAl, m0, k3);
    PH_PRE();
    MMA_I(1, 0, b0h, b0l);
    PH_POST();

    // P8: (qm1,j1) buf1 | vmcnt(2) -> buf0 (t2) fully landed
    PH_PRE();
    MMA_I(1, 1, b1h, b1l);
    __builtin_amdgcn_s_setprio(0);
    asm volatile("s_waitcnt vmcnt(2)" ::: "memory");
    __builtin_amdgcn_s_barrier();
    __builtin_amdgcn_sched_barrier(0);
  }

  // epilogue: C/D map col=lane&15, row=(lane>>4)*4+reg (dtype-independent)
  const int er = (lane >> 4) * 4;
  const int ec = lane & 15;
#pragma unroll
  for (int fi = 0; fi < 8; ++fi) {
    const int grow0 = m0 + (fi >> 2) * 128 + wr * 64 + (fi & 3) * 16 + er;
#pragma unroll
    for (int j = 0; j < 2; ++j) {
      const int gcol = n0 + wc * 32 + j * 16 + ec;
      const float bv = bias ? bias[gcol] : 0.0f;
#pragma unroll
      for (int r = 0; r < 4; ++r) {
        const float x =
            sAB * ((float)accH[fi][j][r] + (float)accX[fi][j][r] * 0.00390625f) + bv;
        const size_t off = (size_t)zb * sC + (size_t)(grow0 + r) * N + gcol;
        if constexpr (EPI == 0) {
          Cf[off] = x;
        } else {
          int2 qq = q8i(x, INV_S_QK);
          Ch[off] = (i8)qq.x;
          Cl[off] = (i8)qq.y;
        }
      }
    }
  }
}

// ---------------------------------------------------------------------------
// gemm8p: plain-bf16 256x128-tile, BK=64, 4-phase counted-vmcnt (round 6).
// ---------------------------------------------------------------------------
#define STG_P(DSTBASE, SRC, ROWBASE, KREAL)                                    \
  do {                                                                         \
    const u16* s0_ = (SRC) + (size_t)((ROWBASE) + sr) * K + (KREAL) + (sc << 3); \
    const u16* s1_ = s0_ + (size_t)64 * K;                                     \
    __builtin_amdgcn_global_load_lds(AS1(s0_), AS3(&lds[(DSTBASE) + ldsW]), 16, 0, 0); \
    __builtin_amdgcn_global_load_lds(AS1(s1_), AS3(&lds[(DSTBASE) + 4096 + ldsW]), 16, 0, 0); \
  } while (0)

#define LDA_P(BUF, QM, S)                                                      \
  do {                                                                         \
    const int base_ = (BUF) * 24576 + (QM) * 8192;                             \
    _Pragma("unroll") for (int i_ = 0; i_ < 4; ++i_) {                         \
      const int r_ = wr * 64 + i_ * 16 + fr;                                   \
      a[i_] = *(const bf16x8*)&lds[base_ + r_ * 64 + (((((S) * 4 + ksl)) ^ (r_ & 7)) << 3)]; \
    }                                                                          \
  } while (0)

#define LDB_P(BUF, S)                                                          \
  do {                                                                         \
    const int base_ = (BUF) * 24576 + 16384;                                   \
    _Pragma("unroll") for (int j_ = 0; j_ < 2; ++j_) {                         \
      const int r_ = wc * 32 + j_ * 16 + fr;                                   \
      b[j_] = *(const bf16x8*)&lds[base_ + r_ * 64 + (((((S) * 4 + ksl)) ^ (r_ & 7)) << 3)]; \
    }                                                                          \
  } while (0)

#define MMA_P(QM)                                                              \
  do {                                                                         \
    _Pragma("unroll") for (int i_ = 0; i_ < 4; ++i_) {                         \
      _Pragma("unroll") for (int j_ = 0; j_ < 2; ++j_) {                       \
        acc[(QM) * 4 + i_][j_] = __builtin_amdgcn_mfma_f32_16x16x32_bf16(      \
            a[i_], b[j_], acc[(QM) * 4 + i_][j_], 0, 0, 0);                    \
      }                                                                        \
    }                                                                          \
  } while (0)

template <int EPI>
__global__ __launch_bounds__(512, 2) void gemm8p(
    const u16* __restrict__ A, const u16* __restrict__ B,
    const float* __restrict__ bias, float* __restrict__ Cf,
    u16* __restrict__ Ch, int M, int N, int K,
    long long sA, long long sB, long long sC) {
  extern __shared__ u16 lds[];

  const int tt = threadIdx.x;
  const int lane = tt & 63;
  const int wv = tt >> 6;
  const int wr = wv >> 2;
  const int wc = wv & 3;
  const int fr = lane & 15;
  const int ksl = lane >> 4;

  const long long zb = blockIdx.z;
  const u16* pA = A + zb * sA;
  const u16* pB = B + zb * sB;
  const int m0 = blockIdx.x * 256;
  const int n0 = blockIdx.y * 128;

  const int sr = tt >> 3;
  const int ss = tt & 7;
  const int sc = ss ^ (sr & 7);
  const int ldsW = (tt & ~63) * 8;

  f32x4 acc[8][2] = {};
  bf16x8 a[4], b[2];

  const int NT = K / 64;

  STG_P(16384, pB, n0, 0);
  STG_P(0, pA, m0, 0);
  STG_P(8192, pA, m0 + 128, 0);
  asm volatile("s_waitcnt vmcnt(2)" ::: "memory");
  __builtin_amdgcn_s_barrier();
  __builtin_amdgcn_sched_barrier(0);

  for (int it = 0; it < NT; ++it) {
    const int cur = it & 1;
    const int nb = (cur ^ 1) * 24576;
    const int kn = (it + 1 < NT ? it + 1 : NT - 1) * 64;

    LDA_P(cur, 0, 0);
    LDB_P(cur, 0);
    STG_P(nb + 16384, pB, n0, kn);
    PH_PRE();
    MMA_P(0);
    __builtin_amdgcn_s_setprio(0);
    asm volatile("s_waitcnt vmcnt(2)" ::: "memory");
    __builtin_amdgcn_s_barrier();
    __builtin_amdgcn_sched_barrier(0);

    LDA_P(cur, 1, 0);
    STG_P(nb + 0, pA, m0, kn);
    PH_PRE();
    MMA_P(1);
    PH_POST();

    LDA_P(cur, 0, 1);
    LDB_P(cur, 1);
    STG_P(nb + 8192, pA, m0 + 128, kn);
    PH_PRE();
    MMA_P(0);
    PH_POST();

    LDA_P(cur, 1, 1);
    PH_PRE();
    MMA_P(1);
    __builtin_amdgcn_s_setprio(0);
    asm volatile("s_waitcnt vmcnt(2)" ::: "memory");
    __builtin_amdgcn_s_barrier();
    __builtin_amdgcn_sched_barrier(0);
  }

  const int er = (lane >> 4) * 4;
  const int ec = lane & 15;
#pragma unroll
  for (int fi = 0; fi < 8; ++fi) {
    const int qm = fi >> 2, i = fi & 3;
    const int grow0 = m0 + qm * 128 + wr * 64 + i * 16 + er;
#pragma unroll
    for (int j = 0; j < 2; ++j) {
      const int gcol = n0 + wc * 32 + j * 16 + ec;
      const float bv = bias ? bias[gcol] : 0.0f;
#pragma unroll
      for (int r = 0; r < 4; ++r) {
        const float x = acc[fi][j][r] + bv;
        const size_t off = (size_t)zb * sC + (size_t)(grow0 + r) * N + gcol;
        if constexpr (EPI == 0) Cf[off] = x;
        else Ch[off] = f2bf(x);
      }
    }
  }
}

// ---------------------------------------------------------------------------
// Row softmax: in-place fp32 (weights output) + bf16 copy (P for PV GEMM).
// ---------------------------------------------------------------------------
__global__ __launch_bounds__(256) void softmax_rows(float* __restrict__ S,
                                                    u16* __restrict__ P) {
  const int T = 2048;
  const size_t row = blockIdx.x;
  float* sr = S + row * T;
  u16* pr = P + row * T;
  const int t = threadIdx.x;
  const int w = t >> 6, lane = t & 63;
  __shared__ float red[8];

  float v[8];
  float mx = -1e30f;
#pragma unroll
  for (int i = 0; i < 8; ++i) {
    v[i] = sr[t + 256 * i];
    mx = fmaxf(mx, v[i]);
  }
#pragma unroll
  for (int off = 32; off; off >>= 1) mx = fmaxf(mx, __shfl_xor(mx, off));
  if (lane == 0) red[w] = mx;
  __syncthreads();
  mx = fmaxf(fmaxf(red[0], red[1]), fmaxf(red[2], red[3]));

  float s = 0.f;
#pragma unroll
  for (int i = 0; i < 8; ++i) {
    v[i] = __expf(v[i] - mx);
    s += v[i];
  }
#pragma unroll
  for (int off = 32; off; off >>= 1) s += __shfl_xor(s, off);
  if (lane == 0) red[4 + w] = s;
  __syncthreads();
  s = (red[4] + red[5]) + (red[6] + red[7]);
  const float inv = 1.0f / s;
#pragma unroll
  for (int i = 0; i < 8; ++i) {
    const float wv = v[i] * inv;
    sr[t + 256 * i] = wv;
    pr[t + 256 * i] = f2bf(wv);
  }
}

// ---------------------------------------------------------------------------
extern "C" void kernel_launch(void* const* d_in, const int* in_sizes, int n_in,
                              void* d_out, int out_size, void* d_ws,
                              size_t ws_size, hipStream_t stream) {
  (void)in_sizes; (void)n_in; (void)out_size; (void)ws_size;
  const float* query = (const float*)d_in[0];
  const float* key   = (const float*)d_in[1];
  const float* value = (const float*)d_in[2];
  const float* Wq    = (const float*)d_in[3];
  const float* bq    = (const float*)d_in[4];
  const float* Wo    = (const float*)d_in[5];
  const float* bo    = (const float*)d_in[6];

  const int S = 2048, D = 1024;
  const size_t n = (size_t)4 * S * D;   // 8,388,608 elements

  float* out = (float*)d_out;           // (B,S,D) f32, 32MB
  float* wts = out + n;                 // (B,S,T) f32, 64MB

  char* ws = (char*)d_ws;
  i8* wqt_h = (i8*)(ws);                     // 1MB  Wq^T hi (i8)
  i8* wqt_l = (i8*)(ws + (1ull << 20));      // 1MB  Wq^T lo
  u16* wot  = (u16*)(ws + (2ull << 20));     // 2MB  Wo^T bf16
  u16* wq_b = (u16*)(ws + (4ull << 20));     // 2MB  Wq bf16
  u16* wqoT = (u16*)(ws + (6ull << 20));     // 2MB  (Wq@Wo)^T bf16
  float* bqo = (float*)(ws + (8ull << 20));  // 4KB
  i8* QKh = (i8*)(ws + (9ull << 20));        // 16MB  [Q;K] hi
  i8* QKl = (i8*)(ws + (25ull << 20));       // 16MB  [Q;K] lo
  u16* tmp = (u16*)(ws + (41ull << 20));     // 16MB  P@value^T (total ws 57MB)
  u16* P = (u16*)(ws + (9ull << 20));        // 32MB overlay QKh+QKl (dead)

  // scratch in d_out: wts region holds input splits until score GEMM writes;
  // out region holds value^T until the final GEMM writes.
  i8* ah = (i8*)wts;        // [q;k] hi, 16MB
  i8* al = ah + 2 * n;      // [q;k] lo, 16MB
  u16* valT = (u16*)out;    // (B, D, T) bf16, 16MB

  hipFuncSetAttribute((const void*)&gemm8i<2>,
                      hipFuncAttributeMaxDynamicSharedMemorySize, 98304);
  hipFuncSetAttribute((const void*)&gemm8i<0>,
                      hipFuncAttributeMaxDynamicSharedMemorySize, 98304);
  hipFuncSetAttribute((const void*)&gemm8p<1>,
                      hipFuncAttributeMaxDynamicSharedMemorySize, 98304);
  hipFuncSetAttribute((const void*)&gemm8p<0>,
                      hipFuncAttributeMaxDynamicSharedMemorySize, 98304);

  // 1. split q,k inputs (stacked) to i8 h/l
  split_qk_i8<<<2048, 256, 0, stream>>>(query, key, ah, al, ah + n, al + n,
                                        (int)(n / 4));
  // 2. weight prep (i8 Wq^T split + bf16 Wo^T / Wq)
  prep_w_i8<<<dim3(D / 32, D / 32), dim3(32, 8), 0, stream>>>(
      Wq, Wo, wqt_h, wqt_l, wot, wq_b, D);
  // 3. value^T (f32 -> bf16), per batch
  transpose_f32_bf16<<<dim3(D / 32, S / 32, 4), dim3(32, 8), 0, stream>>>(
      value, valT, S, D);
  // 4. WqoT = (Wq@Wo)^T bf16
  gemm_bt<1><<<dim3(8, 8, 1), 256, 0, stream>>>(
      wot, wq_b, nullptr, nullptr, wqoT, 1024, 1024, 1024, 0, 0, 0);
  // 5. bqo = bq@Wo + bo
  bqo_kernel<<<256, 256, 0, stream>>>(bq, wot, bo, bqo, D);
  // 6. [Q;K] = [q;k] @ Wq + bq  (i8 dual-split GEMM, i8 split out)
  gemm8i<2><<<dim3(64, 8, 1), 512, 98304, stream>>>(
      ah, al, wqt_h, wqt_l, bq, S_IN * S_W, nullptr, QKh, QKl,
      16384, 1024, 1024, 0, 0, 0);
  // 7. score = Q @ K^T (i8 dual-split GEMM, f32 out)
  gemm8i<0><<<dim3(8, 16, 4), 512, 98304, stream>>>(
      QKh, QKl, QKh + n, QKl + n, nullptr, S_QK * S_QK, wts, nullptr, nullptr,
      2048, 2048, 1024, (long long)S * D, (long long)S * D, (long long)S * S);
  // 8. softmax rows (in-place) + bf16 P
  softmax_rows<<<8192, 256, 0, stream>>>(wts, P);
  // 9. tmp = P @ value^T — gemm8p
  gemm8p<1><<<dim3(8, 8, 4), 512, 98304, stream>>>(
      P, valT, nullptr, nullptr, tmp, 2048, 1024, 2048, (long long)S * S,
      (long long)D * S, (long long)S * D);
  // 10. out = tmp @ Wqo + bqo — gemm8p
  gemm8p<0><<<dim3(32, 8, 1), 512, 98304, stream>>>(
      tmp, wqoT, bqo, out, nullptr, 8192, 1024, 1024, 0, 0, 0);
}